// Round 13
// baseline (1854.882 us; speedup 1.0000x reference)
//
#include <hip/hip_runtime.h>
#include <hip/hip_bf16.h>
#include <math.h>

#define HID 256
#define NH 8
#define DH 32
#define NL 2
#define NV 20000
#define NT 50000
#define NE 100000
#define NC 8
#define FIN 64

typedef unsigned short u16;
typedef unsigned int u32;
typedef short s16x8 __attribute__((ext_vector_type(8)));
typedef float f32x4 __attribute__((ext_vector_type(4)));

__device__ __forceinline__ float bf2f(u16 u) { return __uint_as_float(((u32)u) << 16); }
__device__ __forceinline__ u16 f2bf(float f) {
    u32 x = __float_as_uint(f);
    u32 r = ((x >> 16) & 1u) + 0x7fffu;
    return (u16)((x + r) >> 16);
}
__device__ __forceinline__ void up2(u32 u, float& a, float& b) {
    a = __uint_as_float(u << 16);
    b = __uint_as_float(u & 0xffff0000u);
}
__device__ __forceinline__ s16x8 gelu8(s16x8 a) {
    s16x8 r;
#pragma unroll
    for (int i = 0; i < 8; i++) {
        float v = bf2f((u16)a[i]);
        v = 0.5f * v * (1.f + erff(v * 0.70710678118654752f));
        r[i] = (short)f2bf(v);
    }
    return r;
}

// ---------------- zero fill ----------------
__global__ void k_zero_i(int* __restrict__ p, int n) {
    for (int i = blockIdx.x * 256 + threadIdx.x; i < n; i += gridDim.x * 256) p[i] = 0;
}

// ---------------- histogram of dst ----------------
__global__ void k_hist(const int* __restrict__ dst, int* __restrict__ cnt) {
    for (int e = blockIdx.x * 256 + threadIdx.x; e < NE; e += gridDim.x * 256)
        atomicAdd(&cnt[dst[e]], 1);
}

// ---------------- exclusive prefix scan ----------------
__global__ __launch_bounds__(1024) void k_scan(const int* __restrict__ cnt, int* __restrict__ rp, int n) {
    __shared__ int wsum[16];
    __shared__ int carry_s;
    int t = threadIdx.x, lane = t & 63, wv = t >> 6;
    if (t == 0) { carry_s = 0; rp[0] = 0; }
    __syncthreads();
    for (int base = 0; base < n; base += 1024) {
        int v = (base + t < n) ? cnt[base + t] : 0;
        int x = v;
#pragma unroll
        for (int off = 1; off < 64; off <<= 1) {
            int y = __shfl_up(x, off, 64);
            if (lane >= off) x += y;
        }
        if (lane == 63) wsum[wv] = x;
        __syncthreads();
        if (wv == 0 && lane < 16) {
            int s = wsum[lane];
#pragma unroll
            for (int off = 1; off < 16; off <<= 1) {
                int y = __shfl_up(s, off, 64);
                if (lane >= off) s += y;
            }
            wsum[lane] = s;
        }
        __syncthreads();
        int prefix = carry_s + (wv > 0 ? wsum[wv - 1] : 0);
        if (base + t < n) rp[base + t + 1] = prefix + x;
        __syncthreads();
        if (t == 0) carry_s += wsum[15];
        __syncthreads();
    }
}

// ---------------- copy int ----------------
__global__ void k_copy_i(const int* __restrict__ a, int* __restrict__ b, int n) {
    for (int i = blockIdx.x * 256 + threadIdx.x; i < n; i += gridDim.x * 256) b[i] = a[i];
}

// ---------------- scatter srcs into CSR slots ----------------
__global__ void k_scatter(const int* __restrict__ dst, const int* __restrict__ src,
                          int* __restrict__ fill, int* __restrict__ es) {
    for (int e = blockIdx.x * 256 + threadIdx.x; e < NE; e += gridDim.x * 256) {
        int d = dst[e];
        int p = atomicAdd(&fill[d], 1);
        es[p] = src[e];
    }
}

// ---------------- input projection ----------------
__global__ __launch_bounds__(256) void k_in_proj(const float* __restrict__ X, const float* __restrict__ W,
                          const float* __restrict__ b, u16* __restrict__ Y, int N) {
    const int NPB = 16;
    __shared__ float xs[NPB][FIN];
    int n0 = blockIdx.x * NPB;
    int t = threadIdx.x;
    for (int idx = t; idx < NPB * FIN; idx += 256) {
        int i = idx >> 6, c = idx & 63;
        int n = n0 + i;
        xs[i][c] = (n < N) ? X[(size_t)n * FIN + c] : 0.f;
    }
    __syncthreads();
    float acc[NPB];
#pragma unroll
    for (int i = 0; i < NPB; i++) acc[i] = 0.f;
    for (int c = 0; c < FIN; c++) {
        float w = W[c * HID + t];
#pragma unroll
        for (int i = 0; i < NPB; i++) acc[i] += xs[i][c] * w;
    }
    float bb = b[t];
    for (int i = 0; i < NPB; i++) {
        int n = n0 + i;
        if (n < N) Y[(size_t)n * HID + t] = f2bf(fmaxf(acc[i] + bb, 0.f));
    }
}

// swizzle index for MFMA B fragment: given (k,n) -> flat idx in Wsw
__device__ __forceinline__ int swz_idx(int k, int n) {
    int ks = k >> 5, r = k & 31;
    int j = r & 7;
    int l = ((r >> 3) << 4) | (n & 15);
    int nt = n >> 4;
    return ((ks * 16 + nt) * 64 + l) * 8 + j;
}

// ---------------- fuse rel matrix into projection weight, emit SWIZZLED bf16 ----------------
__global__ __launch_bounds__(256) void k_fuse_w(const float* __restrict__ W, const float* __restrict__ b,
                        const float* __restrict__ R, u16* __restrict__ Wsw, float* __restrict__ bout) {
    int h = blockIdx.x; // 8 blocks
    __shared__ float sR[DH * DH];
    int t = threadIdx.x;
    for (int idx = t; idx < DH * DH; idx += 256) sR[idx] = R[h * DH * DH + idx];
    __syncthreads();
    int f = t & 31, c0 = t >> 5;
    for (int c = c0; c < HID; c += 8) {
        float acc = 0.f;
#pragma unroll
        for (int d = 0; d < DH; d++) acc += W[c * HID + h * DH + d] * sR[d * DH + f];
        Wsw[swz_idx(c, h * DH + f)] = f2bf(acc);
    }
    if (t < DH) {
        float acc = 0.f;
#pragma unroll
        for (int d = 0; d < DH; d++) acc += b[h * DH + d] * sR[d * DH + t];
        bout[h * DH + t] = acc;
    }
}

// ---------------- batched swizzle of 9 static weights: Wq[0..3], Wa[0..3], Ws1 ----------------
__global__ __launch_bounds__(256) void k_swz_multi(const float* __restrict__ Wq, const float* __restrict__ Wa,
                                                   const float* __restrict__ Ws1, u16* __restrict__ out) {
    int slot = blockIdx.x >> 8;
    int idx = ((blockIdx.x & 255) << 8) | threadIdx.x; // 0..65535
    const float* src = (slot < 4) ? (Wq + (size_t)slot * 65536)
                     : (slot < 8) ? (Wa + (size_t)(slot - 4) * 65536)
                                  : Ws1;
    int j = idx & 7, l = (idx >> 3) & 63, nt = (idx >> 9) & 15, ks = idx >> 13;
    int k = ks * 32 + (l >> 4) * 8 + j;
    int n = nt * 16 + (l & 15);
    out[(size_t)slot * 65536 + idx] = f2bf(src[k * HID + n]);
}

// ---------------- MFMA GEMM, B-resident-in-LDS: Y[N,256] = X(bf16)[N,256] @ Wsw + bias ----
// Each block stages one 128-col half of Wsw (64 KB) in LDS, then grid-strides 64-row tiles.
// MODE 0: bf16 out. MODE 1: f32 out, no bias. MODE 2: skip-mix into Y(bf16). GELU: gelu(A) at load.
template <int MODE, int GELU>
__global__ __launch_bounds__(256, 2) void k_mm(const u16* __restrict__ X, const u16* __restrict__ Wsw,
                                               const float* __restrict__ bias, void* __restrict__ Y,
                                               const float* __restrict__ skip_, int N) {
    __shared__ u16 sB[32768]; // 64 KB: [ks 0..7][ntl 0..7][lane 0..63][8]
    int tid = threadIdx.x;
    int half = blockIdx.x & 1;
    // stage: dest chunk d (8 u16) <- global chunk d + (d>>9)*512 + half*512
#pragma unroll
    for (int i = 0; i < 16; i++) {
        int d = i * 256 + tid;
        int g = d + ((d >> 9) + half) * 512;
        *(s16x8*)(sB + (size_t)d * 8) = *(const s16x8*)(Wsw + (size_t)g * 8);
    }
    __syncthreads();
    int w = tid >> 6, lane = tid & 63;
    int laneR = lane & 15, koffg = lane >> 4;
    int nblk = (N + 63) >> 6;
    float beta = 0.f, ombeta = 0.f;
    if (MODE == 2) { beta = 1.f / (1.f + expf(-skip_[0])); ombeta = 1.f - beta; }
    for (int rb = blockIdx.x >> 1; rb < nblk; rb += gridDim.x >> 1) {
        int r0 = rb * 64 + w * 16;
        int rA = r0 + laneR;
        s16x8 a[8];
        if (rA < N) {
            const s16x8* ap = (const s16x8*)(X + (size_t)rA * HID) + koffg;
#pragma unroll
            for (int ks = 0; ks < 8; ks++) a[ks] = ap[ks * 4];
        } else {
#pragma unroll
            for (int ks = 0; ks < 8; ks++) a[ks] = (s16x8){0, 0, 0, 0, 0, 0, 0, 0};
        }
        if (GELU) {
#pragma unroll
            for (int ks = 0; ks < 8; ks++) a[ks] = gelu8(a[ks]);
        }
        f32x4 acc[8];
#pragma unroll
        for (int nt = 0; nt < 8; nt++) acc[nt] = (f32x4){0.f, 0.f, 0.f, 0.f};
#pragma unroll
        for (int ks = 0; ks < 8; ks++) {
            const s16x8* bq = (const s16x8*)sB + ks * 512 + lane;
#pragma unroll
            for (int nt = 0; nt < 8; nt++) {
                acc[nt] = __builtin_amdgcn_mfma_f32_16x16x32_bf16(a[ks], bq[nt * 64], acc[nt], 0, 0, 0);
            }
        }
        int colb = laneR;
        int rowb = r0 + koffg * 4;
#pragma unroll
        for (int nt = 0; nt < 8; nt++) {
            int col = half * 128 + nt * 16 + colb;
            float bb = (MODE == 1) ? 0.f : bias[col];
#pragma unroll
            for (int j = 0; j < 4; j++) {
                int row = rowb + j;
                if (row < N) {
                    float v = acc[nt][j] + bb;
                    if (MODE == 0) {
                        ((u16*)Y)[(size_t)row * HID + col] = f2bf(v);
                    } else if (MODE == 1) {
                        ((float*)Y)[(size_t)row * HID + col] = v;
                    } else {
                        u16* hp = (u16*)Y + (size_t)row * HID + col;
                        *hp = f2bf(beta * v + ombeta * bf2f(*hp));
                    }
                }
            }
        }
    }
}

// ---------------- per-dst-node online-softmax aggregation ----------------
__global__ __launch_bounds__(256) void k_node_attn(
        const u16* __restrict__ q, const u16* __restrict__ kA, const u16* __restrict__ vM,
        const int* __restrict__ rp, const int* __restrict__ es,
        const float* __restrict__ P, float scale,
        u16* __restrict__ agg, int Nd, int add) {
    int node = blockIdx.x * 4 + (threadIdx.x >> 6);
    if (node >= Nd) return;
    int lane = threadIdx.x & 63;
    int h = lane >> 3;
    float ph = P[h] * scale;
    uint2 qu = *(const uint2*)(q + (size_t)node * HID + lane * 4);
    float q0, q1, q2, q3; up2(qu.x, q0, q1); up2(qu.y, q2, q3);
    float m = -INFINITY, ss = 0.f, a0 = 0.f, a1 = 0.f, a2 = 0.f, a3 = 0.f;
    int jb = rp[node], je = rp[node + 1];
    for (int j = jb; j < je; j++) {
        int s = es[j];
        uint2 ku = *(const uint2*)(kA + (size_t)s * HID + lane * 4);
        float k0, k1, k2, k3; up2(ku.x, k0, k1); up2(ku.y, k2, k3);
        float part = q0 * k0 + q1 * k1 + q2 * k2 + q3 * k3;
        part += __shfl_xor(part, 1, 64);
        part += __shfl_xor(part, 2, 64);
        part += __shfl_xor(part, 4, 64);
        float logit = part * ph;
        float nm = fmaxf(m, logit);
        float corr = expf(m - nm);
        float ee = expf(logit - nm);
        uint2 vu = *(const uint2*)(vM + (size_t)s * HID + lane * 4);
        float v0, v1, v2, v3; up2(vu.x, v0, v1); up2(vu.y, v2, v3);
        ss = ss * corr + ee;
        a0 = a0 * corr + ee * v0; a1 = a1 * corr + ee * v1;
        a2 = a2 * corr + ee * v2; a3 = a3 * corr + ee * v3;
        m = nm;
    }
    float inv = 1.f / (ss + 1e-16f);
    a0 *= inv; a1 *= inv; a2 *= inv; a3 *= inv;
    u16* ap = agg + (size_t)node * HID + lane * 4;
    if (add) {
        a0 += bf2f(ap[0]); a1 += bf2f(ap[1]); a2 += bf2f(ap[2]); a3 += bf2f(ap[3]);
    }
    ap[0] = f2bf(a0); ap[1] = f2bf(a1); ap[2] = f2bf(a2); ap[3] = f2bf(a3);
}

// ---------------- vpart ----------------
__global__ void k_vpart(const u16* __restrict__ hv, const int* __restrict__ current,
                        const float* __restrict__ Ws1, const float* __restrict__ bs1,
                        float* __restrict__ vpart) {
    __shared__ float row[HID];
    int t = threadIdx.x;
    for (int c = 0; c < NC; c++) {
        int n = current[c * 2];
        row[t] = bf2f(hv[(size_t)n * HID + t]);
        __syncthreads();
        float acc = 0.f;
        for (int i = 0; i < HID; i++) acc += row[i] * Ws1[(size_t)(HID + i) * HID + t];
        vpart[c * HID + t] = acc + bs1[t];
        __syncthreads();
    }
}

// ---------------- final (R10-proven form) ----------------
__global__ __launch_bounds__(256) void k_final(const float* __restrict__ tpart, const float* __restrict__ vpart,
                        const float* __restrict__ Ws2, const float* __restrict__ bs2,
                        float* __restrict__ out) {
    __shared__ float vp[NC * HID];
    int t = threadIdx.x;
    for (int idx = t; idx < NC * HID; idx += 256) vp[idx] = vpart[idx];
    __syncthreads();
    int lane = t & 63, w = t >> 6;
    float w20[4], w21[4];
#pragma unroll
    for (int i = 0; i < 4; i++) {
        w20[i] = Ws2[(lane + 64 * i) * 2 + 0];
        w21[i] = Ws2[(lane + 64 * i) * 2 + 1];
    }
    float b0 = bs2[0], b1 = bs2[1];
    for (int n = blockIdx.x * 4 + w; n < NT; n += gridDim.x * 4) {
        float tp[4];
#pragma unroll
        for (int i = 0; i < 4; i++) tp[i] = tpart[(size_t)n * HID + lane + 64 * i];
#pragma unroll
        for (int c = 0; c < NC; c++) {
            float a0 = 0.f, a1 = 0.f;
#pragma unroll
            for (int i = 0; i < 4; i++) {
                float hm = fmaxf(tp[i] + vp[c * HID + lane + 64 * i], 0.f);
                a0 += hm * w20[i];
                a1 += hm * w21[i];
            }
#pragma unroll
            for (int off = 32; off >= 1; off >>= 1) {
                a0 += __shfl_xor(a0, off, 64);
                a1 += __shfl_xor(a1, off, 64);
            }
            if (lane == 0) {
                out[(size_t)c * NT + n] = a0 + b0;
                float z = a1 + b1;
                out[(size_t)NC * NT + (size_t)c * NT + n] = 1.f / (1.f + expf(-z));
            }
        }
    }
}

extern "C" void kernel_launch(void* const* d_in, const int* in_sizes, int n_in,
                              void* d_out, int out_size, void* d_ws, size_t ws_size,
                              hipStream_t stream) {
    (void)in_sizes; (void)n_in; (void)out_size;
    const float* x_v    = (const float*)d_in[0];
    const float* x_t    = (const float*)d_in[1];
    const int* ei_vt_s  = (const int*)d_in[2];
    const int* ei_vt_d  = (const int*)d_in[3];
    const int* ei_tv_s  = (const int*)d_in[4];
    const int* ei_tv_d  = (const int*)d_in[5];
    const int* ei_tt_s  = (const int*)d_in[6];
    const int* ei_tt_d  = (const int*)d_in[7];
    const int* current  = (const int*)d_in[8];
    const float* W_in_v = (const float*)d_in[9];
    const float* b_in_v = (const float*)d_in[10];
    const float* W_in_t = (const float*)d_in[11];
    const float* b_in_t = (const float*)d_in[12];
    const float* Wk     = (const float*)d_in[13];
    const float* bk     = (const float*)d_in[14];
    const float* Wq     = (const float*)d_in[15];
    const float* bq     = (const float*)d_in[16];
    const float* Wv     = (const float*)d_in[17];
    const float* bv     = (const float*)d_in[18];
    const float* Wa     = (const float*)d_in[19];
    const float* ba     = (const float*)d_in[20];
    const float* skip   = (const float*)d_in[21];
    const float* a_rel  = (const float*)d_in[22];
    const float* m_rel  = (const float*)d_in[23];
    const float* p_rel  = (const float*)d_in[24];
    const float* Ws1    = (const float*)d_in[25];
    const float* bs1    = (const float*)d_in[26];
    const float* Ws2    = (const float*)d_in[27];
    const float* bs2    = (const float*)d_in[28];

    char* p = (char*)d_ws;
    auto alloc = [&](size_t bytes) -> char* {
        char* r = p;
        p += (bytes + 255) & ~(size_t)255;
        return r;
    };
    u16* hv   = (u16*)alloc((size_t)NV * HID * 2);
    u16* ht   = (u16*)alloc((size_t)NT * HID * 2);
    u16* qb   = (u16*)alloc((size_t)NT * HID * 2);
    u16* kA   = (u16*)alloc((size_t)NT * HID * 2); // kA+vM contiguous -> f32 tpart later
    u16* vM   = (u16*)alloc((size_t)NT * HID * 2);
    u16* agg  = (u16*)alloc((size_t)NT * HID * 2);
    int* rp_vt = (int*)alloc((size_t)(NT + 1) * 4);
    int* rp_tv = (int*)alloc((size_t)(NV + 1) * 4);
    int* rp_tt = (int*)alloc((size_t)(NT + 1) * 4);
    int* es_vt = (int*)alloc((size_t)NE * 4);
    int* es_tv = (int*)alloc((size_t)NE * 4);
    int* es_tt = (int*)alloc((size_t)NE * 4);
    int* cnt   = (int*)alloc((size_t)NT * 4);
    int* fill  = (int*)alloc((size_t)NT * 4);
    float* vp  = (float*)alloc((size_t)NC * HID * 4);
    float* bf  = (float*)alloc(HID * 4);                  // fused bias temp
    u16*  wsw  = (u16*)alloc((size_t)HID * HID * 2);      // fused swizzled weight temp
    u16*  wswA = (u16*)alloc((size_t)9 * HID * HID * 2);  // static swizzled: Wq0..3, Wa0..3, Ws1
    if ((size_t)(p - (char*)d_ws) > ws_size) return;

    const float scale = 0.17677669529663687f;

    // ---- build 3 CSRs ----
    {
        const int* DL[3] = { ei_vt_d, ei_tv_d, ei_tt_d };
        const int* SL[3] = { ei_vt_s, ei_tv_s, ei_tt_s };
        int* RP[3] = { rp_vt, rp_tv, rp_tt };
        int* ES[3] = { es_vt, es_tv, es_tt };
        int ND[3] = { NT, NV, NT };
        for (int r = 0; r < 3; r++) {
            k_zero_i<<<256, 256, 0, stream>>>(cnt, ND[r]);
            k_hist<<<512, 256, 0, stream>>>(DL[r], cnt);
            k_scan<<<1, 1024, 0, stream>>>(cnt, RP[r], ND[r]);
            k_copy_i<<<256, 256, 0, stream>>>(RP[r], fill, ND[r]);
            k_scatter<<<512, 256, 0, stream>>>(DL[r], SL[r], fill, ES[r]);
        }
    }

    // ---- swizzle all static weights in one launch ----
    k_swz_multi<<<9 * 256, 256, 0, stream>>>(Wq, Wa, Ws1, wswA);

    k_in_proj<<<(NV + 15) / 16, 256, 0, stream>>>(x_v, W_in_v, b_in_v, hv, NV);
    k_in_proj<<<(NT + 15) / 16, 256, 0, stream>>>(x_t, W_in_t, b_in_t, ht, NT);

    const int GMM = 512; // 2 n-halves x 256 row-block streams

    for (int l = 0; l < NL; l++) {
        const float* Wk0 = Wk + (size_t)(l * 2 + 0) * HID * HID;
        const float* Wk1 = Wk + (size_t)(l * 2 + 1) * HID * HID;
        const float* bk0 = bk + (l * 2 + 0) * HID, *bk1 = bk + (l * 2 + 1) * HID;
        const float* Wv0 = Wv + (size_t)(l * 2 + 0) * HID * HID;
        const float* Wv1 = Wv + (size_t)(l * 2 + 1) * HID * HID;
        const float* bv0 = bv + (l * 2 + 0) * HID, *bv1 = bv + (l * 2 + 1) * HID;
        const float* bq0 = bq + (l * 2 + 0) * HID, *bq1 = bq + (l * 2 + 1) * HID;
        const u16* WqS0 = wswA + (size_t)(l * 2 + 0) * 65536;
        const u16* WqS1 = wswA + (size_t)(l * 2 + 1) * 65536;
        const u16* WaS0 = wswA + (size_t)(4 + l * 2 + 0) * 65536;
        const u16* WaS1 = wswA + (size_t)(4 + l * 2 + 1) * 65536;
        const float* A0 = a_rel + (size_t)(l * 3 + 0) * NH * DH * DH;
        const float* A1 = a_rel + (size_t)(l * 3 + 1) * NH * DH * DH;
        const float* A2 = a_rel + (size_t)(l * 3 + 2) * NH * DH * DH;
        const float* M0 = m_rel + (size_t)(l * 3 + 0) * NH * DH * DH;
        const float* M1 = m_rel + (size_t)(l * 3 + 1) * NH * DH * DH;
        const float* M2 = m_rel + (size_t)(l * 3 + 2) * NH * DH * DH;
        const float* P0 = p_rel + (size_t)(l * 3 + 0) * NH;
        const float* P1 = p_rel + (size_t)(l * 3 + 1) * NH;
        const float* P2 = p_rel + (size_t)(l * 3 + 2) * NH;

        // 1. q_v from OLD hv; r1 (t->v): fused k/v from OLD ht; aggregate
        k_mm<0, 0><<<GMM, 256, 0, stream>>>(hv, WqS0, bq0, qb, nullptr, NV);
        k_fuse_w<<<NH, 256, 0, stream>>>(Wk1, bk1, A1, wsw, bf);
        k_mm<0, 0><<<GMM, 256, 0, stream>>>(ht, wsw, bf, kA, nullptr, NT);
        k_fuse_w<<<NH, 256, 0, stream>>>(Wv1, bv1, M1, wsw, bf);
        k_mm<0, 0><<<GMM, 256, 0, stream>>>(ht, wsw, bf, vM, nullptr, NT);
        k_node_attn<<<(NV + 3) / 4, 256, 0, stream>>>(qb, kA, vM, rp_tv, es_tv, P1, scale, agg, NV, 0);

        // 2. q_t from OLD ht; r0 (v->t): fused k/v from OLD hv
        k_mm<0, 0><<<GMM, 256, 0, stream>>>(ht, WqS1, bq1, qb, nullptr, NT);
        k_fuse_w<<<NH, 256, 0, stream>>>(Wk0, bk0, A0, wsw, bf);
        k_mm<0, 0><<<GMM, 256, 0, stream>>>(hv, wsw, bf, kA, nullptr, NV);
        k_fuse_w<<<NH, 256, 0, stream>>>(Wv0, bv0, M0, wsw, bf);
        k_mm<0, 0><<<GMM, 256, 0, stream>>>(hv, wsw, bf, vM, nullptr, NV);

        // 3. update hv: MFMA GEMM with fused gelu-on-A and skip-mix epilogue
        k_mm<2, 1><<<GMM, 256, 0, stream>>>(agg, WaS0, ba + (l * 2 + 0) * HID, hv, skip + (l * 2 + 0), NV);

        // 4. aggregate r0 into agg (overwrite)
        k_node_attn<<<(NT + 3) / 4, 256, 0, stream>>>(qb, kA, vM, rp_vt, es_vt, P0, scale, agg, NT, 0);

        // 5. r2 (t->t): fused k/v from OLD ht; aggregate (add)
        k_fuse_w<<<NH, 256, 0, stream>>>(Wk1, bk1, A2, wsw, bf);
        k_mm<0, 0><<<GMM, 256, 0, stream>>>(ht, wsw, bf, kA, nullptr, NT);
        k_fuse_w<<<NH, 256, 0, stream>>>(Wv1, bv1, M2, wsw, bf);
        k_mm<0, 0><<<GMM, 256, 0, stream>>>(ht, wsw, bf, vM, nullptr, NT);
        k_node_attn<<<(NT + 3) / 4, 256, 0, stream>>>(qb, kA, vM, rp_tt, es_tt, P2, scale, agg, NT, 1);

        // 6. update ht
        k_mm<2, 1><<<GMM, 256, 0, stream>>>(agg, WaS1, ba + (l * 2 + 1) * HID, ht, skip + (l * 2 + 1), NT);
    }

    k_vpart<<<1, 256, 0, stream>>>(hv, current, Ws1, bs1, vp);
    float* tpart = (float*)kA; // kA+vM contiguous = NT*HID*4 bytes
    k_mm<1, 0><<<GMM, 256, 0, stream>>>(ht, wswA + (size_t)8 * 65536, nullptr, (void*)tpart, nullptr, NT);
    k_final<<<2048, 256, 0, stream>>>(tpart, vp, Ws2, bs2, (float*)d_out);
}

// Round 14
// 1649.747 us; speedup vs baseline: 1.1243x; 1.1243x over previous
//
#include <hip/hip_runtime.h>
#include <hip/hip_bf16.h>
#include <math.h>

#define HID 256
#define NH 8
#define DH 32
#define NL 2
#define NV 20000
#define NT 50000
#define NE 100000
#define NC 8
#define FIN 64

typedef unsigned short u16;
typedef unsigned int u32;
typedef short s16x8 __attribute__((ext_vector_type(8)));
typedef float f32x4 __attribute__((ext_vector_type(4)));

__device__ __forceinline__ float bf2f(u16 u) { return __uint_as_float(((u32)u) << 16); }
__device__ __forceinline__ u16 f2bf(float f) {
    u32 x = __float_as_uint(f);
    u32 r = ((x >> 16) & 1u) + 0x7fffu;
    return (u16)((x + r) >> 16);
}
__device__ __forceinline__ void up2(u32 u, float& a, float& b) {
    a = __uint_as_float(u << 16);
    b = __uint_as_float(u & 0xffff0000u);
}
__device__ __forceinline__ s16x8 gelu8(s16x8 a) {
    s16x8 r;
#pragma unroll
    for (int i = 0; i < 8; i++) {
        float v = bf2f((u16)a[i]);
        v = 0.5f * v * (1.f + erff(v * 0.70710678118654752f));
        r[i] = (short)f2bf(v);
    }
    return r;
}

// ---------------- zero fill ----------------
__global__ void k_zero_i(int* __restrict__ p, int n) {
    for (int i = blockIdx.x * 256 + threadIdx.x; i < n; i += gridDim.x * 256) p[i] = 0;
}

// ---------------- histogram of dst ----------------
__global__ void k_hist(const int* __restrict__ dst, int* __restrict__ cnt) {
    for (int e = blockIdx.x * 256 + threadIdx.x; e < NE; e += gridDim.x * 256)
        atomicAdd(&cnt[dst[e]], 1);
}

// ---------------- exclusive prefix scan ----------------
__global__ __launch_bounds__(1024) void k_scan(const int* __restrict__ cnt, int* __restrict__ rp, int n) {
    __shared__ int wsum[16];
    __shared__ int carry_s;
    int t = threadIdx.x, lane = t & 63, wv = t >> 6;
    if (t == 0) { carry_s = 0; rp[0] = 0; }
    __syncthreads();
    for (int base = 0; base < n; base += 1024) {
        int v = (base + t < n) ? cnt[base + t] : 0;
        int x = v;
#pragma unroll
        for (int off = 1; off < 64; off <<= 1) {
            int y = __shfl_up(x, off, 64);
            if (lane >= off) x += y;
        }
        if (lane == 63) wsum[wv] = x;
        __syncthreads();
        if (wv == 0 && lane < 16) {
            int s = wsum[lane];
#pragma unroll
            for (int off = 1; off < 16; off <<= 1) {
                int y = __shfl_up(s, off, 64);
                if (lane >= off) s += y;
            }
            wsum[lane] = s;
        }
        __syncthreads();
        int prefix = carry_s + (wv > 0 ? wsum[wv - 1] : 0);
        if (base + t < n) rp[base + t + 1] = prefix + x;
        __syncthreads();
        if (t == 0) carry_s += wsum[15];
        __syncthreads();
    }
}

// ---------------- copy int ----------------
__global__ void k_copy_i(const int* __restrict__ a, int* __restrict__ b, int n) {
    for (int i = blockIdx.x * 256 + threadIdx.x; i < n; i += gridDim.x * 256) b[i] = a[i];
}

// ---------------- scatter srcs into CSR slots ----------------
__global__ void k_scatter(const int* __restrict__ dst, const int* __restrict__ src,
                          int* __restrict__ fill, int* __restrict__ es) {
    for (int e = blockIdx.x * 256 + threadIdx.x; e < NE; e += gridDim.x * 256) {
        int d = dst[e];
        int p = atomicAdd(&fill[d], 1);
        es[p] = src[e];
    }
}

// ---------------- input projection ----------------
__global__ __launch_bounds__(256) void k_in_proj(const float* __restrict__ X, const float* __restrict__ W,
                          const float* __restrict__ b, u16* __restrict__ Y, int N) {
    const int NPB = 16;
    __shared__ float xs[NPB][FIN];
    int n0 = blockIdx.x * NPB;
    int t = threadIdx.x;
    for (int idx = t; idx < NPB * FIN; idx += 256) {
        int i = idx >> 6, c = idx & 63;
        int n = n0 + i;
        xs[i][c] = (n < N) ? X[(size_t)n * FIN + c] : 0.f;
    }
    __syncthreads();
    float acc[NPB];
#pragma unroll
    for (int i = 0; i < NPB; i++) acc[i] = 0.f;
    for (int c = 0; c < FIN; c++) {
        float w = W[c * HID + t];
#pragma unroll
        for (int i = 0; i < NPB; i++) acc[i] += xs[i][c] * w;
    }
    float bb = b[t];
    for (int i = 0; i < NPB; i++) {
        int n = n0 + i;
        if (n < N) Y[(size_t)n * HID + t] = f2bf(fmaxf(acc[i] + bb, 0.f));
    }
}

// swizzle index for MFMA B fragment: given (k,n) -> flat idx in Wsw
__device__ __forceinline__ int swz_idx(int k, int n) {
    int ks = k >> 5, r = k & 31;
    int j = r & 7;
    int l = ((r >> 3) << 4) | (n & 15);
    int nt = n >> 4;
    return ((ks * 16 + nt) * 64 + l) * 8 + j;
}

// ---------------- fuse rel matrix into projection weight, emit SWIZZLED bf16 ----------------
__global__ __launch_bounds__(256) void k_fuse_w(const float* __restrict__ W, const float* __restrict__ b,
                        const float* __restrict__ R, u16* __restrict__ Wsw, float* __restrict__ bout) {
    int h = blockIdx.x; // 8 blocks
    __shared__ float sR[DH * DH];
    int t = threadIdx.x;
    for (int idx = t; idx < DH * DH; idx += 256) sR[idx] = R[h * DH * DH + idx];
    __syncthreads();
    int f = t & 31, c0 = t >> 5;
    for (int c = c0; c < HID; c += 8) {
        float acc = 0.f;
#pragma unroll
        for (int d = 0; d < DH; d++) acc += W[c * HID + h * DH + d] * sR[d * DH + f];
        Wsw[swz_idx(c, h * DH + f)] = f2bf(acc);
    }
    if (t < DH) {
        float acc = 0.f;
#pragma unroll
        for (int d = 0; d < DH; d++) acc += b[h * DH + d] * sR[d * DH + t];
        bout[h * DH + t] = acc;
    }
}

// ---------------- batched swizzle of 9 static weights: Wq[0..3], Wa[0..3], Ws1 ----------------
__global__ __launch_bounds__(256) void k_swz_multi(const float* __restrict__ Wq, const float* __restrict__ Wa,
                                                   const float* __restrict__ Ws1, u16* __restrict__ out) {
    int slot = blockIdx.x >> 8;
    int idx = ((blockIdx.x & 255) << 8) | threadIdx.x; // 0..65535
    const float* src = (slot < 4) ? (Wq + (size_t)slot * 65536)
                     : (slot < 8) ? (Wa + (size_t)(slot - 4) * 65536)
                                  : Ws1;
    int j = idx & 7, l = (idx >> 3) & 63, nt = (idx >> 9) & 15, ks = idx >> 13;
    int k = ks * 32 + (l >> 4) * 8 + j;
    int n = nt * 16 + (l & 15);
    out[(size_t)slot * 65536 + idx] = f2bf(src[k * HID + n]);
}

// ---------------- MFMA GEMM (R12-proven): Y[N,256] = X(bf16)[N,256] @ Wsw + bias ----------------
// MODE 0: bf16 out. MODE 1: f32 out, no bias. MODE 2: skip-mix into Y(bf16). GELU: gelu(A) at load.
template <int MODE, int GELU>
__global__ __launch_bounds__(256) void k_mm(const u16* __restrict__ X, const u16* __restrict__ Wsw,
                                            const float* __restrict__ bias, void* __restrict__ Y,
                                            const float* __restrict__ skip_, int N) {
    int tid = threadIdx.x;
    int w = tid >> 6, lane = tid & 63;
    int r0 = blockIdx.x * 64 + w * 16;
    int rA = r0 + (lane & 15);
    int koff = (lane >> 4) * 8;
    f32x4 acc[16];
#pragma unroll
    for (int nt = 0; nt < 16; nt++) acc[nt] = (f32x4){0.f, 0.f, 0.f, 0.f};
    const s16x8* wp = (const s16x8*)Wsw;
#pragma unroll
    for (int ks = 0; ks < 8; ks++) {
        s16x8 a = (s16x8){0, 0, 0, 0, 0, 0, 0, 0};
        if (rA < N) a = *(const s16x8*)(X + (size_t)rA * HID + ks * 32 + koff);
        if (GELU) a = gelu8(a);
        const s16x8* wq = wp + (size_t)ks * 16 * 64 + lane;
#pragma unroll
        for (int nt = 0; nt < 16; nt++) {
            s16x8 b = wq[nt * 64];
            acc[nt] = __builtin_amdgcn_mfma_f32_16x16x32_bf16(a, b, acc[nt], 0, 0, 0);
        }
    }
    int colb = lane & 15;
    int rowb = r0 + (lane >> 4) * 4;
    float beta = 0.f, ombeta = 0.f;
    if (MODE == 2) { beta = 1.f / (1.f + expf(-skip_[0])); ombeta = 1.f - beta; }
#pragma unroll
    for (int nt = 0; nt < 16; nt++) {
        int col = nt * 16 + colb;
        float bb = (MODE == 1) ? 0.f : bias[col];
#pragma unroll
        for (int j = 0; j < 4; j++) {
            int row = rowb + j;
            if (row < N) {
                float v = acc[nt][j] + bb;
                if (MODE == 0) {
                    ((u16*)Y)[(size_t)row * HID + col] = f2bf(v);
                } else if (MODE == 1) {
                    ((float*)Y)[(size_t)row * HID + col] = v;
                } else {
                    u16* hp = (u16*)Y + (size_t)row * HID + col;
                    *hp = f2bf(beta * v + ombeta * bf2f(*hp));
                }
            }
        }
    }
}

// ---------------- dual-B MFMA GEMM: Y1 = X@W1+b1, Y2 = X@W2+b2 (A loaded once) ----------------
__global__ __launch_bounds__(256) void k_mm2(const u16* __restrict__ X,
                                             const u16* __restrict__ W1, const float* __restrict__ b1, u16* __restrict__ Y1,
                                             const u16* __restrict__ W2, const float* __restrict__ b2, u16* __restrict__ Y2,
                                             int N) {
    int tid = threadIdx.x;
    int w = tid >> 6, lane = tid & 63;
    int r0 = blockIdx.x * 64 + w * 16;
    int rA = r0 + (lane & 15);
    int koff = (lane >> 4) * 8;
    // load A fragments once (persist in registers across both passes)
    s16x8 a[8];
    if (rA < N) {
        const s16x8* ap = (const s16x8*)(X + (size_t)rA * HID) + (koff >> 3);
#pragma unroll
        for (int ks = 0; ks < 8; ks++) a[ks] = ap[ks * 4];
    } else {
#pragma unroll
        for (int ks = 0; ks < 8; ks++) a[ks] = (s16x8){0, 0, 0, 0, 0, 0, 0, 0};
    }
    int colb = lane & 15;
    int rowb = r0 + (lane >> 4) * 4;
#pragma unroll
    for (int pass = 0; pass < 2; pass++) {
        const u16* Wsw = pass ? W2 : W1;
        const float* bias = pass ? b2 : b1;
        u16* Y = pass ? Y2 : Y1;
        f32x4 acc[16];
#pragma unroll
        for (int nt = 0; nt < 16; nt++) acc[nt] = (f32x4){0.f, 0.f, 0.f, 0.f};
        const s16x8* wp = (const s16x8*)Wsw;
#pragma unroll
        for (int ks = 0; ks < 8; ks++) {
            const s16x8* wq = wp + (size_t)ks * 16 * 64 + lane;
#pragma unroll
            for (int nt = 0; nt < 16; nt++) {
                s16x8 b = wq[nt * 64];
                acc[nt] = __builtin_amdgcn_mfma_f32_16x16x32_bf16(a[ks], b, acc[nt], 0, 0, 0);
            }
        }
#pragma unroll
        for (int nt = 0; nt < 16; nt++) {
            int col = nt * 16 + colb;
            float bb = bias[col];
#pragma unroll
            for (int j = 0; j < 4; j++) {
                int row = rowb + j;
                if (row < N) Y[(size_t)row * HID + col] = f2bf(acc[nt][j] + bb);
            }
        }
    }
}

// ---------------- per-dst-node online-softmax aggregation ----------------
__global__ __launch_bounds__(256) void k_node_attn(
        const u16* __restrict__ q, const u16* __restrict__ kA, const u16* __restrict__ vM,
        const int* __restrict__ rp, const int* __restrict__ es,
        const float* __restrict__ P, float scale,
        u16* __restrict__ agg, int Nd, int add) {
    int node = blockIdx.x * 4 + (threadIdx.x >> 6);
    if (node >= Nd) return;
    int lane = threadIdx.x & 63;
    int h = lane >> 3;
    float ph = P[h] * scale;
    uint2 qu = *(const uint2*)(q + (size_t)node * HID + lane * 4);
    float q0, q1, q2, q3; up2(qu.x, q0, q1); up2(qu.y, q2, q3);
    float m = -INFINITY, ss = 0.f, a0 = 0.f, a1 = 0.f, a2 = 0.f, a3 = 0.f;
    int jb = rp[node], je = rp[node + 1];
    for (int j = jb; j < je; j++) {
        int s = es[j];
        uint2 ku = *(const uint2*)(kA + (size_t)s * HID + lane * 4);
        float k0, k1, k2, k3; up2(ku.x, k0, k1); up2(ku.y, k2, k3);
        float part = q0 * k0 + q1 * k1 + q2 * k2 + q3 * k3;
        part += __shfl_xor(part, 1, 64);
        part += __shfl_xor(part, 2, 64);
        part += __shfl_xor(part, 4, 64);
        float logit = part * ph;
        float nm = fmaxf(m, logit);
        float corr = expf(m - nm);
        float ee = expf(logit - nm);
        uint2 vu = *(const uint2*)(vM + (size_t)s * HID + lane * 4);
        float v0, v1, v2, v3; up2(vu.x, v0, v1); up2(vu.y, v2, v3);
        ss = ss * corr + ee;
        a0 = a0 * corr + ee * v0; a1 = a1 * corr + ee * v1;
        a2 = a2 * corr + ee * v2; a3 = a3 * corr + ee * v3;
        m = nm;
    }
    float inv = 1.f / (ss + 1e-16f);
    a0 *= inv; a1 *= inv; a2 *= inv; a3 *= inv;
    u16* ap = agg + (size_t)node * HID + lane * 4;
    if (add) {
        a0 += bf2f(ap[0]); a1 += bf2f(ap[1]); a2 += bf2f(ap[2]); a3 += bf2f(ap[3]);
    }
    ap[0] = f2bf(a0); ap[1] = f2bf(a1); ap[2] = f2bf(a2); ap[3] = f2bf(a3);
}

// ---------------- vpart ----------------
__global__ void k_vpart(const u16* __restrict__ hv, const int* __restrict__ current,
                        const float* __restrict__ Ws1, const float* __restrict__ bs1,
                        float* __restrict__ vpart) {
    __shared__ float row[HID];
    int t = threadIdx.x;
    for (int c = 0; c < NC; c++) {
        int n = current[c * 2];
        row[t] = bf2f(hv[(size_t)n * HID + t]);
        __syncthreads();
        float acc = 0.f;
        for (int i = 0; i < HID; i++) acc += row[i] * Ws1[(size_t)(HID + i) * HID + t];
        vpart[c * HID + t] = acc + bs1[t];
        __syncthreads();
    }
}

// ---------------- final (R10-proven form) ----------------
__global__ __launch_bounds__(256) void k_final(const float* __restrict__ tpart, const float* __restrict__ vpart,
                        const float* __restrict__ Ws2, const float* __restrict__ bs2,
                        float* __restrict__ out) {
    __shared__ float vp[NC * HID];
    int t = threadIdx.x;
    for (int idx = t; idx < NC * HID; idx += 256) vp[idx] = vpart[idx];
    __syncthreads();
    int lane = t & 63, w = t >> 6;
    float w20[4], w21[4];
#pragma unroll
    for (int i = 0; i < 4; i++) {
        w20[i] = Ws2[(lane + 64 * i) * 2 + 0];
        w21[i] = Ws2[(lane + 64 * i) * 2 + 1];
    }
    float b0 = bs2[0], b1 = bs2[1];
    for (int n = blockIdx.x * 4 + w; n < NT; n += gridDim.x * 4) {
        float tp[4];
#pragma unroll
        for (int i = 0; i < 4; i++) tp[i] = tpart[(size_t)n * HID + lane + 64 * i];
#pragma unroll
        for (int c = 0; c < NC; c++) {
            float a0 = 0.f, a1 = 0.f;
#pragma unroll
            for (int i = 0; i < 4; i++) {
                float hm = fmaxf(tp[i] + vp[c * HID + lane + 64 * i], 0.f);
                a0 += hm * w20[i];
                a1 += hm * w21[i];
            }
#pragma unroll
            for (int off = 32; off >= 1; off >>= 1) {
                a0 += __shfl_xor(a0, off, 64);
                a1 += __shfl_xor(a1, off, 64);
            }
            if (lane == 0) {
                out[(size_t)c * NT + n] = a0 + b0;
                float z = a1 + b1;
                out[(size_t)NC * NT + (size_t)c * NT + n] = 1.f / (1.f + expf(-z));
            }
        }
    }
}

extern "C" void kernel_launch(void* const* d_in, const int* in_sizes, int n_in,
                              void* d_out, int out_size, void* d_ws, size_t ws_size,
                              hipStream_t stream) {
    (void)in_sizes; (void)n_in; (void)out_size;
    const float* x_v    = (const float*)d_in[0];
    const float* x_t    = (const float*)d_in[1];
    const int* ei_vt_s  = (const int*)d_in[2];
    const int* ei_vt_d  = (const int*)d_in[3];
    const int* ei_tv_s  = (const int*)d_in[4];
    const int* ei_tv_d  = (const int*)d_in[5];
    const int* ei_tt_s  = (const int*)d_in[6];
    const int* ei_tt_d  = (const int*)d_in[7];
    const int* current  = (const int*)d_in[8];
    const float* W_in_v = (const float*)d_in[9];
    const float* b_in_v = (const float*)d_in[10];
    const float* W_in_t = (const float*)d_in[11];
    const float* b_in_t = (const float*)d_in[12];
    const float* Wk     = (const float*)d_in[13];
    const float* bk     = (const float*)d_in[14];
    const float* Wq     = (const float*)d_in[15];
    const float* bq     = (const float*)d_in[16];
    const float* Wv     = (const float*)d_in[17];
    const float* bv     = (const float*)d_in[18];
    const float* Wa     = (const float*)d_in[19];
    const float* ba     = (const float*)d_in[20];
    const float* skip   = (const float*)d_in[21];
    const float* a_rel  = (const float*)d_in[22];
    const float* m_rel  = (const float*)d_in[23];
    const float* p_rel  = (const float*)d_in[24];
    const float* Ws1    = (const float*)d_in[25];
    const float* bs1    = (const float*)d_in[26];
    const float* Ws2    = (const float*)d_in[27];
    const float* bs2    = (const float*)d_in[28];

    char* p = (char*)d_ws;
    auto alloc = [&](size_t bytes) -> char* {
        char* r = p;
        p += (bytes + 255) & ~(size_t)255;
        return r;
    };
    u16* hv   = (u16*)alloc((size_t)NV * HID * 2);
    u16* ht   = (u16*)alloc((size_t)NT * HID * 2);
    u16* qb   = (u16*)alloc((size_t)NT * HID * 2);
    u16* kA   = (u16*)alloc((size_t)NT * HID * 2); // kA+vM contiguous -> f32 tpart later
    u16* vM   = (u16*)alloc((size_t)NT * HID * 2);
    u16* agg  = (u16*)alloc((size_t)NT * HID * 2);
    int* rp_vt = (int*)alloc((size_t)(NT + 1) * 4);
    int* rp_tv = (int*)alloc((size_t)(NV + 1) * 4);
    int* rp_tt = (int*)alloc((size_t)(NT + 1) * 4);
    int* es_vt = (int*)alloc((size_t)NE * 4);
    int* es_tv = (int*)alloc((size_t)NE * 4);
    int* es_tt = (int*)alloc((size_t)NE * 4);
    int* cnt   = (int*)alloc((size_t)NT * 4);
    int* fill  = (int*)alloc((size_t)NT * 4);
    float* vp  = (float*)alloc((size_t)NC * HID * 4);
    float* bkF = (float*)alloc(HID * 4);                  // fused k bias
    float* bvF = (float*)alloc(HID * 4);                  // fused v bias
    u16*  wswK = (u16*)alloc((size_t)HID * HID * 2);      // fused swizzled k weight
    u16*  wswV = (u16*)alloc((size_t)HID * HID * 2);      // fused swizzled v weight
    u16*  wswA = (u16*)alloc((size_t)9 * HID * HID * 2);  // static swizzled: Wq0..3, Wa0..3, Ws1
    if ((size_t)(p - (char*)d_ws) > ws_size) return;

    const float scale = 0.17677669529663687f;

    // ---- build 3 CSRs ----
    {
        const int* DL[3] = { ei_vt_d, ei_tv_d, ei_tt_d };
        const int* SL[3] = { ei_vt_s, ei_tv_s, ei_tt_s };
        int* RP[3] = { rp_vt, rp_tv, rp_tt };
        int* ES[3] = { es_vt, es_tv, es_tt };
        int ND[3] = { NT, NV, NT };
        for (int r = 0; r < 3; r++) {
            k_zero_i<<<256, 256, 0, stream>>>(cnt, ND[r]);
            k_hist<<<512, 256, 0, stream>>>(DL[r], cnt);
            k_scan<<<1, 1024, 0, stream>>>(cnt, RP[r], ND[r]);
            k_copy_i<<<256, 256, 0, stream>>>(RP[r], fill, ND[r]);
            k_scatter<<<512, 256, 0, stream>>>(DL[r], SL[r], fill, ES[r]);
        }
    }

    // ---- swizzle all static weights in one launch ----
    k_swz_multi<<<9 * 256, 256, 0, stream>>>(Wq, Wa, Ws1, wswA);

    k_in_proj<<<(NV + 15) / 16, 256, 0, stream>>>(x_v, W_in_v, b_in_v, hv, NV);
    k_in_proj<<<(NT + 15) / 16, 256, 0, stream>>>(x_t, W_in_t, b_in_t, ht, NT);

    const int GV = (NV + 63) / 64, GT = (NT + 63) / 64;

    for (int l = 0; l < NL; l++) {
        const float* Wk0 = Wk + (size_t)(l * 2 + 0) * HID * HID;
        const float* Wk1 = Wk + (size_t)(l * 2 + 1) * HID * HID;
        const float* bk0 = bk + (l * 2 + 0) * HID, *bk1 = bk + (l * 2 + 1) * HID;
        const float* Wv0 = Wv + (size_t)(l * 2 + 0) * HID * HID;
        const float* Wv1 = Wv + (size_t)(l * 2 + 1) * HID * HID;
        const float* bv0 = bv + (l * 2 + 0) * HID, *bv1 = bv + (l * 2 + 1) * HID;
        const float* bq0 = bq + (l * 2 + 0) * HID, *bq1 = bq + (l * 2 + 1) * HID;
        const u16* WqS0 = wswA + (size_t)(l * 2 + 0) * 65536;
        const u16* WqS1 = wswA + (size_t)(l * 2 + 1) * 65536;
        const u16* WaS0 = wswA + (size_t)(4 + l * 2 + 0) * 65536;
        const u16* WaS1 = wswA + (size_t)(4 + l * 2 + 1) * 65536;
        const float* A0 = a_rel + (size_t)(l * 3 + 0) * NH * DH * DH;
        const float* A1 = a_rel + (size_t)(l * 3 + 1) * NH * DH * DH;
        const float* A2 = a_rel + (size_t)(l * 3 + 2) * NH * DH * DH;
        const float* M0 = m_rel + (size_t)(l * 3 + 0) * NH * DH * DH;
        const float* M1 = m_rel + (size_t)(l * 3 + 1) * NH * DH * DH;
        const float* M2 = m_rel + (size_t)(l * 3 + 2) * NH * DH * DH;
        const float* P0 = p_rel + (size_t)(l * 3 + 0) * NH;
        const float* P1 = p_rel + (size_t)(l * 3 + 1) * NH;
        const float* P2 = p_rel + (size_t)(l * 3 + 2) * NH;

        // 1. q_v from OLD hv; r1 (t->v): fused k+v dual GEMM from OLD ht; aggregate
        k_mm<0, 0><<<GV, 256, 0, stream>>>(hv, WqS0, bq0, qb, nullptr, NV);
        k_fuse_w<<<NH, 256, 0, stream>>>(Wk1, bk1, A1, wswK, bkF);
        k_fuse_w<<<NH, 256, 0, stream>>>(Wv1, bv1, M1, wswV, bvF);
        k_mm2<<<GT, 256, 0, stream>>>(ht, wswK, bkF, kA, wswV, bvF, vM, NT);
        k_node_attn<<<(NV + 3) / 4, 256, 0, stream>>>(qb, kA, vM, rp_tv, es_tv, P1, scale, agg, NV, 0);

        // 2. q_t from OLD ht; r0 (v->t): fused k+v dual GEMM from OLD hv
        k_mm<0, 0><<<GT, 256, 0, stream>>>(ht, WqS1, bq1, qb, nullptr, NT);
        k_fuse_w<<<NH, 256, 0, stream>>>(Wk0, bk0, A0, wswK, bkF);
        k_fuse_w<<<NH, 256, 0, stream>>>(Wv0, bv0, M0, wswV, bvF);
        k_mm2<<<GV, 256, 0, stream>>>(hv, wswK, bkF, kA, wswV, bvF, vM, NV);

        // 3. update hv: MFMA GEMM with fused gelu-on-A and skip-mix epilogue
        k_mm<2, 1><<<GV, 256, 0, stream>>>(agg, WaS0, ba + (l * 2 + 0) * HID, hv, skip + (l * 2 + 0), NV);

        // 4. aggregate r0 into agg (overwrite)
        k_node_attn<<<(NT + 3) / 4, 256, 0, stream>>>(qb, kA, vM, rp_vt, es_vt, P0, scale, agg, NT, 0);

        // 5. r2 (t->t): fused k+v dual GEMM from OLD ht; aggregate (add)
        k_fuse_w<<<NH, 256, 0, stream>>>(Wk1, bk1, A2, wswK, bkF);
        k_fuse_w<<<NH, 256, 0, stream>>>(Wv1, bv1, M2, wswV, bvF);
        k_mm2<<<GT, 256, 0, stream>>>(ht, wswK, bkF, kA, wswV, bvF, vM, NT);
        k_node_attn<<<(NT + 3) / 4, 256, 0, stream>>>(qb, kA, vM, rp_tt, es_tt, P2, scale, agg, NT, 1);

        // 6. update ht
        k_mm<2, 1><<<GT, 256, 0, stream>>>(agg, WaS1, ba + (l * 2 + 1) * HID, ht, skip + (l * 2 + 1), NT);
    }

    k_vpart<<<1, 256, 0, stream>>>(hv, current, Ws1, bs1, vp);
    float* tpart = (float*)kA; // kA+vM contiguous = NT*HID*4 bytes
    k_mm<1, 0><<<GT, 256, 0, stream>>>(ht, wswA + (size_t)8 * 65536, nullptr, (void*)tpart, nullptr, NT);
    k_final<<<2048, 256, 0, stream>>>(tpart, vp, Ws2, bs2, (float*)d_out);
}

// Round 15
// 1243.565 us; speedup vs baseline: 1.4916x; 1.3266x over previous
//
#include <hip/hip_runtime.h>
#include <hip/hip_bf16.h>
#include <math.h>

#define HID 256
#define NH 8
#define DH 32
#define NL 2
#define NV 20000
#define NT 50000
#define NE 100000
#define NC 8
#define FIN 64

typedef unsigned short u16;
typedef unsigned int u32;
typedef short s16x8 __attribute__((ext_vector_type(8)));
typedef float f32x4 __attribute__((ext_vector_type(4)));

__device__ __forceinline__ float bf2f(u16 u) { return __uint_as_float(((u32)u) << 16); }
__device__ __forceinline__ u16 f2bf(float f) {
    u32 x = __float_as_uint(f);
    u32 r = ((x >> 16) & 1u) + 0x7fffu;
    return (u16)((x + r) >> 16);
}
__device__ __forceinline__ void up2(u32 u, float& a, float& b) {
    a = __uint_as_float(u << 16);
    b = __uint_as_float(u & 0xffff0000u);
}
__device__ __forceinline__ s16x8 gelu8(s16x8 a) {
    s16x8 r;
#pragma unroll
    for (int i = 0; i < 8; i++) {
        float v = bf2f((u16)a[i]);
        v = 0.5f * v * (1.f + erff(v * 0.70710678118654752f));
        r[i] = (short)f2bf(v);
    }
    return r;
}

// ---------------- zero fill ----------------
__global__ void k_zero_i(int* __restrict__ p, int n) {
    for (int i = blockIdx.x * 256 + threadIdx.x; i < n; i += gridDim.x * 256) p[i] = 0;
}

// ---------------- histogram of dst ----------------
__global__ void k_hist(const int* __restrict__ dst, int* __restrict__ cnt) {
    for (int e = blockIdx.x * 256 + threadIdx.x; e < NE; e += gridDim.x * 256)
        atomicAdd(&cnt[dst[e]], 1);
}

// ---------------- exclusive prefix scan ----------------
__global__ __launch_bounds__(1024) void k_scan(const int* __restrict__ cnt, int* __restrict__ rp, int n) {
    __shared__ int wsum[16];
    __shared__ int carry_s;
    int t = threadIdx.x, lane = t & 63, wv = t >> 6;
    if (t == 0) { carry_s = 0; rp[0] = 0; }
    __syncthreads();
    for (int base = 0; base < n; base += 1024) {
        int v = (base + t < n) ? cnt[base + t] : 0;
        int x = v;
#pragma unroll
        for (int off = 1; off < 64; off <<= 1) {
            int y = __shfl_up(x, off, 64);
            if (lane >= off) x += y;
        }
        if (lane == 63) wsum[wv] = x;
        __syncthreads();
        if (wv == 0 && lane < 16) {
            int s = wsum[lane];
#pragma unroll
            for (int off = 1; off < 16; off <<= 1) {
                int y = __shfl_up(s, off, 64);
                if (lane >= off) s += y;
            }
            wsum[lane] = s;
        }
        __syncthreads();
        int prefix = carry_s + (wv > 0 ? wsum[wv - 1] : 0);
        if (base + t < n) rp[base + t + 1] = prefix + x;
        __syncthreads();
        if (t == 0) carry_s += wsum[15];
        __syncthreads();
    }
}

// ---------------- copy int ----------------
__global__ void k_copy_i(const int* __restrict__ a, int* __restrict__ b, int n) {
    for (int i = blockIdx.x * 256 + threadIdx.x; i < n; i += gridDim.x * 256) b[i] = a[i];
}

// ---------------- scatter srcs into CSR slots ----------------
__global__ void k_scatter(const int* __restrict__ dst, const int* __restrict__ src,
                          int* __restrict__ fill, int* __restrict__ es) {
    for (int e = blockIdx.x * 256 + threadIdx.x; e < NE; e += gridDim.x * 256) {
        int d = dst[e];
        int p = atomicAdd(&fill[d], 1);
        es[p] = src[e];
    }
}

// ---------------- input projection ----------------
__global__ __launch_bounds__(256) void k_in_proj(const float* __restrict__ X, const float* __restrict__ W,
                          const float* __restrict__ b, u16* __restrict__ Y, int N) {
    const int NPB = 16;
    __shared__ float xs[NPB][FIN];
    int n0 = blockIdx.x * NPB;
    int t = threadIdx.x;
    for (int idx = t; idx < NPB * FIN; idx += 256) {
        int i = idx >> 6, c = idx & 63;
        int n = n0 + i;
        xs[i][c] = (n < N) ? X[(size_t)n * FIN + c] : 0.f;
    }
    __syncthreads();
    float acc[NPB];
#pragma unroll
    for (int i = 0; i < NPB; i++) acc[i] = 0.f;
    for (int c = 0; c < FIN; c++) {
        float w = W[c * HID + t];
#pragma unroll
        for (int i = 0; i < NPB; i++) acc[i] += xs[i][c] * w;
    }
    float bb = b[t];
    for (int i = 0; i < NPB; i++) {
        int n = n0 + i;
        if (n < N) Y[(size_t)n * HID + t] = f2bf(fmaxf(acc[i] + bb, 0.f));
    }
}

// swizzle index for MFMA B fragment: given (k,n) -> flat idx in Wsw
__device__ __forceinline__ int swz_idx(int k, int n) {
    int ks = k >> 5, r = k & 31;
    int j = r & 7;
    int l = ((r >> 3) << 4) | (n & 15);
    int nt = n >> 4;
    return ((ks * 16 + nt) * 64 + l) * 8 + j;
}

// ---------------- fuse rel matrix into projection weight, emit SWIZZLED bf16 ----------------
__global__ __launch_bounds__(256) void k_fuse_w(const float* __restrict__ W, const float* __restrict__ b,
                        const float* __restrict__ R, u16* __restrict__ Wsw, float* __restrict__ bout) {
    int h = blockIdx.x; // 8 blocks
    __shared__ float sR[DH * DH];
    int t = threadIdx.x;
    for (int idx = t; idx < DH * DH; idx += 256) sR[idx] = R[h * DH * DH + idx];
    __syncthreads();
    int f = t & 31, c0 = t >> 5;
    for (int c = c0; c < HID; c += 8) {
        float acc = 0.f;
#pragma unroll
        for (int d = 0; d < DH; d++) acc += W[c * HID + h * DH + d] * sR[d * DH + f];
        Wsw[swz_idx(c, h * DH + f)] = f2bf(acc);
    }
    if (t < DH) {
        float acc = 0.f;
#pragma unroll
        for (int d = 0; d < DH; d++) acc += b[h * DH + d] * sR[d * DH + t];
        bout[h * DH + t] = acc;
    }
}

// ---------------- batched swizzle of 9 static weights: Wq[0..3], Wa[0..3], Ws1 ----------------
__global__ __launch_bounds__(256) void k_swz_multi(const float* __restrict__ Wq, const float* __restrict__ Wa,
                                                   const float* __restrict__ Ws1, u16* __restrict__ out) {
    int slot = blockIdx.x >> 8;
    int idx = ((blockIdx.x & 255) << 8) | threadIdx.x; // 0..65535
    const float* src = (slot < 4) ? (Wq + (size_t)slot * 65536)
                     : (slot < 8) ? (Wa + (size_t)(slot - 4) * 65536)
                                  : Ws1;
    int j = idx & 7, l = (idx >> 3) & 63, nt = (idx >> 9) & 15, ks = idx >> 13;
    int k = ks * 32 + (l >> 4) * 8 + j;
    int n = nt * 16 + (l & 15);
    out[(size_t)slot * 65536 + idx] = f2bf(src[k * HID + n]);
}

// ---------------- MFMA GEMM, slim-wave: block = 16 rows x 256 cols, wave = 16x64 ----------------
// acc = 4 f32x4 (16 VGPR) -> compiler headroom to pipeline B loads; high wave count hides L2 latency.
// MODE 0: bf16 out. MODE 1: f32 out, no bias. MODE 2: skip-mix into Y(bf16). GELU: gelu(A) at load.
template <int MODE, int GELU>
__global__ __launch_bounds__(256) void k_mm(const u16* __restrict__ X, const u16* __restrict__ Wsw,
                                            const float* __restrict__ bias, void* __restrict__ Y,
                                            const float* __restrict__ skip_, int N) {
    int tid = threadIdx.x;
    int w = tid >> 6, lane = tid & 63;
    int r0 = blockIdx.x * 16;
    int rA = r0 + (lane & 15);
    int koffg = lane >> 4;
    s16x8 a[8];
    if (rA < N) {
        const s16x8* ap = (const s16x8*)(X + (size_t)rA * HID) + koffg;
#pragma unroll
        for (int ks = 0; ks < 8; ks++) a[ks] = ap[ks * 4];
    } else {
#pragma unroll
        for (int ks = 0; ks < 8; ks++) a[ks] = (s16x8){0, 0, 0, 0, 0, 0, 0, 0};
    }
    if (GELU) {
#pragma unroll
        for (int ks = 0; ks < 8; ks++) a[ks] = gelu8(a[ks]);
    }
    f32x4 acc[4];
#pragma unroll
    for (int nt = 0; nt < 4; nt++) acc[nt] = (f32x4){0.f, 0.f, 0.f, 0.f};
    const s16x8* wp = (const s16x8*)Wsw;
#pragma unroll
    for (int ks = 0; ks < 8; ks++) {
        const s16x8* wq = wp + (size_t)ks * 16 * 64 + lane;
#pragma unroll
        for (int nt = 0; nt < 4; nt++) {
            s16x8 b = wq[(w * 4 + nt) * 64];
            acc[nt] = __builtin_amdgcn_mfma_f32_16x16x32_bf16(a[ks], b, acc[nt], 0, 0, 0);
        }
    }
    int colb = lane & 15;
    int rowb = r0 + koffg * 4;
    float beta = 0.f, ombeta = 0.f;
    if (MODE == 2) { beta = 1.f / (1.f + expf(-skip_[0])); ombeta = 1.f - beta; }
#pragma unroll
    for (int nt = 0; nt < 4; nt++) {
        int col = w * 64 + nt * 16 + colb;
        float bb = (MODE == 1) ? 0.f : bias[col];
#pragma unroll
        for (int j = 0; j < 4; j++) {
            int row = rowb + j;
            if (row < N) {
                float v = acc[nt][j] + bb;
                if (MODE == 0) {
                    ((u16*)Y)[(size_t)row * HID + col] = f2bf(v);
                } else if (MODE == 1) {
                    ((float*)Y)[(size_t)row * HID + col] = v;
                } else {
                    u16* hp = (u16*)Y + (size_t)row * HID + col;
                    *hp = f2bf(beta * v + ombeta * bf2f(*hp));
                }
            }
        }
    }
}

// ---------------- dual-B slim-wave MFMA GEMM: Y1 = X@W1+b1, Y2 = X@W2+b2 (A loaded once) ------
__global__ __launch_bounds__(256) void k_mm2(const u16* __restrict__ X,
                                             const u16* __restrict__ W1, const float* __restrict__ b1, u16* __restrict__ Y1,
                                             const u16* __restrict__ W2, const float* __restrict__ b2, u16* __restrict__ Y2,
                                             int N) {
    int tid = threadIdx.x;
    int w = tid >> 6, lane = tid & 63;
    int r0 = blockIdx.x * 16;
    int rA = r0 + (lane & 15);
    int koffg = lane >> 4;
    s16x8 a[8];
    if (rA < N) {
        const s16x8* ap = (const s16x8*)(X + (size_t)rA * HID) + koffg;
#pragma unroll
        for (int ks = 0; ks < 8; ks++) a[ks] = ap[ks * 4];
    } else {
#pragma unroll
        for (int ks = 0; ks < 8; ks++) a[ks] = (s16x8){0, 0, 0, 0, 0, 0, 0, 0};
    }
    int colb = lane & 15;
    int rowb = r0 + koffg * 4;
#pragma unroll
    for (int pass = 0; pass < 2; pass++) {
        const u16* Wsw = pass ? W2 : W1;
        const float* bias = pass ? b2 : b1;
        u16* Y = pass ? Y2 : Y1;
        f32x4 acc[4];
#pragma unroll
        for (int nt = 0; nt < 4; nt++) acc[nt] = (f32x4){0.f, 0.f, 0.f, 0.f};
        const s16x8* wp = (const s16x8*)Wsw;
#pragma unroll
        for (int ks = 0; ks < 8; ks++) {
            const s16x8* wq = wp + (size_t)ks * 16 * 64 + lane;
#pragma unroll
            for (int nt = 0; nt < 4; nt++) {
                s16x8 b = wq[(w * 4 + nt) * 64];
                acc[nt] = __builtin_amdgcn_mfma_f32_16x16x32_bf16(a[ks], b, acc[nt], 0, 0, 0);
            }
        }
#pragma unroll
        for (int nt = 0; nt < 4; nt++) {
            int col = w * 64 + nt * 16 + colb;
            float bb = bias[col];
#pragma unroll
            for (int j = 0; j < 4; j++) {
                int row = rowb + j;
                if (row < N) Y[(size_t)row * HID + col] = f2bf(acc[nt][j] + bb);
            }
        }
    }
}

// ---------------- per-dst-node online-softmax aggregation ----------------
__global__ __launch_bounds__(256) void k_node_attn(
        const u16* __restrict__ q, const u16* __restrict__ kA, const u16* __restrict__ vM,
        const int* __restrict__ rp, const int* __restrict__ es,
        const float* __restrict__ P, float scale,
        u16* __restrict__ agg, int Nd, int add) {
    int node = blockIdx.x * 4 + (threadIdx.x >> 6);
    if (node >= Nd) return;
    int lane = threadIdx.x & 63;
    int h = lane >> 3;
    float ph = P[h] * scale;
    uint2 qu = *(const uint2*)(q + (size_t)node * HID + lane * 4);
    float q0, q1, q2, q3; up2(qu.x, q0, q1); up2(qu.y, q2, q3);
    float m = -INFINITY, ss = 0.f, a0 = 0.f, a1 = 0.f, a2 = 0.f, a3 = 0.f;
    int jb = rp[node], je = rp[node + 1];
    for (int j = jb; j < je; j++) {
        int s = es[j];
        uint2 ku = *(const uint2*)(kA + (size_t)s * HID + lane * 4);
        float k0, k1, k2, k3; up2(ku.x, k0, k1); up2(ku.y, k2, k3);
        float part = q0 * k0 + q1 * k1 + q2 * k2 + q3 * k3;
        part += __shfl_xor(part, 1, 64);
        part += __shfl_xor(part, 2, 64);
        part += __shfl_xor(part, 4, 64);
        float logit = part * ph;
        float nm = fmaxf(m, logit);
        float corr = expf(m - nm);
        float ee = expf(logit - nm);
        uint2 vu = *(const uint2*)(vM + (size_t)s * HID + lane * 4);
        float v0, v1, v2, v3; up2(vu.x, v0, v1); up2(vu.y, v2, v3);
        ss = ss * corr + ee;
        a0 = a0 * corr + ee * v0; a1 = a1 * corr + ee * v1;
        a2 = a2 * corr + ee * v2; a3 = a3 * corr + ee * v3;
        m = nm;
    }
    float inv = 1.f / (ss + 1e-16f);
    a0 *= inv; a1 *= inv; a2 *= inv; a3 *= inv;
    u16* ap = agg + (size_t)node * HID + lane * 4;
    if (add) {
        a0 += bf2f(ap[0]); a1 += bf2f(ap[1]); a2 += bf2f(ap[2]); a3 += bf2f(ap[3]);
    }
    ap[0] = f2bf(a0); ap[1] = f2bf(a1); ap[2] = f2bf(a2); ap[3] = f2bf(a3);
}

// ---------------- vpart ----------------
__global__ void k_vpart(const u16* __restrict__ hv, const int* __restrict__ current,
                        const float* __restrict__ Ws1, const float* __restrict__ bs1,
                        float* __restrict__ vpart) {
    __shared__ float row[HID];
    int t = threadIdx.x;
    for (int c = 0; c < NC; c++) {
        int n = current[c * 2];
        row[t] = bf2f(hv[(size_t)n * HID + t]);
        __syncthreads();
        float acc = 0.f;
        for (int i = 0; i < HID; i++) acc += row[i] * Ws1[(size_t)(HID + i) * HID + t];
        vpart[c * HID + t] = acc + bs1[t];
        __syncthreads();
    }
}

// ---------------- final (R10-proven form) ----------------
__global__ __launch_bounds__(256) void k_final(const float* __restrict__ tpart, const float* __restrict__ vpart,
                        const float* __restrict__ Ws2, const float* __restrict__ bs2,
                        float* __restrict__ out) {
    __shared__ float vp[NC * HID];
    int t = threadIdx.x;
    for (int idx = t; idx < NC * HID; idx += 256) vp[idx] = vpart[idx];
    __syncthreads();
    int lane = t & 63, w = t >> 6;
    float w20[4], w21[4];
#pragma unroll
    for (int i = 0; i < 4; i++) {
        w20[i] = Ws2[(lane + 64 * i) * 2 + 0];
        w21[i] = Ws2[(lane + 64 * i) * 2 + 1];
    }
    float b0 = bs2[0], b1 = bs2[1];
    for (int n = blockIdx.x * 4 + w; n < NT; n += gridDim.x * 4) {
        float tp[4];
#pragma unroll
        for (int i = 0; i < 4; i++) tp[i] = tpart[(size_t)n * HID + lane + 64 * i];
#pragma unroll
        for (int c = 0; c < NC; c++) {
            float a0 = 0.f, a1 = 0.f;
#pragma unroll
            for (int i = 0; i < 4; i++) {
                float hm = fmaxf(tp[i] + vp[c * HID + lane + 64 * i], 0.f);
                a0 += hm * w20[i];
                a1 += hm * w21[i];
            }
#pragma unroll
            for (int off = 32; off >= 1; off >>= 1) {
                a0 += __shfl_xor(a0, off, 64);
                a1 += __shfl_xor(a1, off, 64);
            }
            if (lane == 0) {
                out[(size_t)c * NT + n] = a0 + b0;
                float z = a1 + b1;
                out[(size_t)NC * NT + (size_t)c * NT + n] = 1.f / (1.f + expf(-z));
            }
        }
    }
}

extern "C" void kernel_launch(void* const* d_in, const int* in_sizes, int n_in,
                              void* d_out, int out_size, void* d_ws, size_t ws_size,
                              hipStream_t stream) {
    (void)in_sizes; (void)n_in; (void)out_size;
    const float* x_v    = (const float*)d_in[0];
    const float* x_t    = (const float*)d_in[1];
    const int* ei_vt_s  = (const int*)d_in[2];
    const int* ei_vt_d  = (const int*)d_in[3];
    const int* ei_tv_s  = (const int*)d_in[4];
    const int* ei_tv_d  = (const int*)d_in[5];
    const int* ei_tt_s  = (const int*)d_in[6];
    const int* ei_tt_d  = (const int*)d_in[7];
    const int* current  = (const int*)d_in[8];
    const float* W_in_v = (const float*)d_in[9];
    const float* b_in_v = (const float*)d_in[10];
    const float* W_in_t = (const float*)d_in[11];
    const float* b_in_t = (const float*)d_in[12];
    const float* Wk     = (const float*)d_in[13];
    const float* bk     = (const float*)d_in[14];
    const float* Wq     = (const float*)d_in[15];
    const float* bq     = (const float*)d_in[16];
    const float* Wv     = (const float*)d_in[17];
    const float* bv     = (const float*)d_in[18];
    const float* Wa     = (const float*)d_in[19];
    const float* ba     = (const float*)d_in[20];
    const float* skip   = (const float*)d_in[21];
    const float* a_rel  = (const float*)d_in[22];
    const float* m_rel  = (const float*)d_in[23];
    const float* p_rel  = (const float*)d_in[24];
    const float* Ws1    = (const float*)d_in[25];
    const float* bs1    = (const float*)d_in[26];
    const float* Ws2    = (const float*)d_in[27];
    const float* bs2    = (const float*)d_in[28];

    char* p = (char*)d_ws;
    auto alloc = [&](size_t bytes) -> char* {
        char* r = p;
        p += (bytes + 255) & ~(size_t)255;
        return r;
    };
    u16* hv   = (u16*)alloc((size_t)NV * HID * 2);
    u16* ht   = (u16*)alloc((size_t)NT * HID * 2);
    u16* qb   = (u16*)alloc((size_t)NT * HID * 2);
    u16* kA   = (u16*)alloc((size_t)NT * HID * 2); // kA+vM contiguous -> f32 tpart later
    u16* vM   = (u16*)alloc((size_t)NT * HID * 2);
    u16* agg  = (u16*)alloc((size_t)NT * HID * 2);
    int* rp_vt = (int*)alloc((size_t)(NT + 1) * 4);
    int* rp_tv = (int*)alloc((size_t)(NV + 1) * 4);
    int* rp_tt = (int*)alloc((size_t)(NT + 1) * 4);
    int* es_vt = (int*)alloc((size_t)NE * 4);
    int* es_tv = (int*)alloc((size_t)NE * 4);
    int* es_tt = (int*)alloc((size_t)NE * 4);
    int* cnt   = (int*)alloc((size_t)NT * 4);
    int* fill  = (int*)alloc((size_t)NT * 4);
    float* vp  = (float*)alloc((size_t)NC * HID * 4);
    float* bkF = (float*)alloc(HID * 4);
    float* bvF = (float*)alloc(HID * 4);
    u16*  wswK = (u16*)alloc((size_t)HID * HID * 2);
    u16*  wswV = (u16*)alloc((size_t)HID * HID * 2);
    u16*  wswA = (u16*)alloc((size_t)9 * HID * HID * 2);
    if ((size_t)(p - (char*)d_ws) > ws_size) return;

    const float scale = 0.17677669529663687f;

    // ---- build 3 CSRs ----
    {
        const int* DL[3] = { ei_vt_d, ei_tv_d, ei_tt_d };
        const int* SL[3] = { ei_vt_s, ei_tv_s, ei_tt_s };
        int* RP[3] = { rp_vt, rp_tv, rp_tt };
        int* ES[3] = { es_vt, es_tv, es_tt };
        int ND[3] = { NT, NV, NT };
        for (int r = 0; r < 3; r++) {
            k_zero_i<<<256, 256, 0, stream>>>(cnt, ND[r]);
            k_hist<<<512, 256, 0, stream>>>(DL[r], cnt);
            k_scan<<<1, 1024, 0, stream>>>(cnt, RP[r], ND[r]);
            k_copy_i<<<256, 256, 0, stream>>>(RP[r], fill, ND[r]);
            k_scatter<<<512, 256, 0, stream>>>(DL[r], SL[r], fill, ES[r]);
        }
    }

    // ---- swizzle all static weights in one launch ----
    k_swz_multi<<<9 * 256, 256, 0, stream>>>(Wq, Wa, Ws1, wswA);

    k_in_proj<<<(NV + 15) / 16, 256, 0, stream>>>(x_v, W_in_v, b_in_v, hv, NV);
    k_in_proj<<<(NT + 15) / 16, 256, 0, stream>>>(x_t, W_in_t, b_in_t, ht, NT);

    const int GV = (NV + 15) / 16, GT = (NT + 15) / 16;

    for (int l = 0; l < NL; l++) {
        const float* Wk0 = Wk + (size_t)(l * 2 + 0) * HID * HID;
        const float* Wk1 = Wk + (size_t)(l * 2 + 1) * HID * HID;
        const float* bk0 = bk + (l * 2 + 0) * HID, *bk1 = bk + (l * 2 + 1) * HID;
        const float* Wv0 = Wv + (size_t)(l * 2 + 0) * HID * HID;
        const float* Wv1 = Wv + (size_t)(l * 2 + 1) * HID * HID;
        const float* bv0 = bv + (l * 2 + 0) * HID, *bv1 = bv + (l * 2 + 1) * HID;
        const float* bq0 = bq + (l * 2 + 0) * HID, *bq1 = bq + (l * 2 + 1) * HID;
        const u16* WqS0 = wswA + (size_t)(l * 2 + 0) * 65536;
        const u16* WqS1 = wswA + (size_t)(l * 2 + 1) * 65536;
        const u16* WaS0 = wswA + (size_t)(4 + l * 2 + 0) * 65536;
        const u16* WaS1 = wswA + (size_t)(4 + l * 2 + 1) * 65536;
        const float* A0 = a_rel + (size_t)(l * 3 + 0) * NH * DH * DH;
        const float* A1 = a_rel + (size_t)(l * 3 + 1) * NH * DH * DH;
        const float* A2 = a_rel + (size_t)(l * 3 + 2) * NH * DH * DH;
        const float* M0 = m_rel + (size_t)(l * 3 + 0) * NH * DH * DH;
        const float* M1 = m_rel + (size_t)(l * 3 + 1) * NH * DH * DH;
        const float* M2 = m_rel + (size_t)(l * 3 + 2) * NH * DH * DH;
        const float* P0 = p_rel + (size_t)(l * 3 + 0) * NH;
        const float* P1 = p_rel + (size_t)(l * 3 + 1) * NH;
        const float* P2 = p_rel + (size_t)(l * 3 + 2) * NH;

        // 1. q_v from OLD hv; r1 (t->v): fused k+v dual GEMM from OLD ht; aggregate
        k_mm<0, 0><<<GV, 256, 0, stream>>>(hv, WqS0, bq0, qb, nullptr, NV);
        k_fuse_w<<<NH, 256, 0, stream>>>(Wk1, bk1, A1, wswK, bkF);
        k_fuse_w<<<NH, 256, 0, stream>>>(Wv1, bv1, M1, wswV, bvF);
        k_mm2<<<GT, 256, 0, stream>>>(ht, wswK, bkF, kA, wswV, bvF, vM, NT);
        k_node_attn<<<(NV + 3) / 4, 256, 0, stream>>>(qb, kA, vM, rp_tv, es_tv, P1, scale, agg, NV, 0);

        // 2. q_t from OLD ht; r0 (v->t): fused k+v dual GEMM from OLD hv
        k_mm<0, 0><<<GT, 256, 0, stream>>>(ht, WqS1, bq1, qb, nullptr, NT);
        k_fuse_w<<<NH, 256, 0, stream>>>(Wk0, bk0, A0, wswK, bkF);
        k_fuse_w<<<NH, 256, 0, stream>>>(Wv0, bv0, M0, wswV, bvF);
        k_mm2<<<GV, 256, 0, stream>>>(hv, wswK, bkF, kA, wswV, bvF, vM, NV);

        // 3. update hv: MFMA GEMM with fused gelu-on-A and skip-mix epilogue
        k_mm<2, 1><<<GV, 256, 0, stream>>>(agg, WaS0, ba + (l * 2 + 0) * HID, hv, skip + (l * 2 + 0), NV);

        // 4. aggregate r0 into agg (overwrite)
        k_node_attn<<<(NT + 3) / 4, 256, 0, stream>>>(qb, kA, vM, rp_vt, es_vt, P0, scale, agg, NT, 0);

        // 5. r2 (t->t): fused k+v dual GEMM from OLD ht; aggregate (add)
        k_fuse_w<<<NH, 256, 0, stream>>>(Wk1, bk1, A2, wswK, bkF);
        k_fuse_w<<<NH, 256, 0, stream>>>(Wv1, bv1, M2, wswV, bvF);
        k_mm2<<<GT, 256, 0, stream>>>(ht, wswK, bkF, kA, wswV, bvF, vM, NT);
        k_node_attn<<<(NT + 3) / 4, 256, 0, stream>>>(qb, kA, vM, rp_tt, es_tt, P2, scale, agg, NT, 1);

        // 6. update ht
        k_mm<2, 1><<<GT, 256, 0, stream>>>(agg, WaS1, ba + (l * 2 + 1) * HID, ht, skip + (l * 2 + 1), NT);
    }

    k_vpart<<<1, 256, 0, stream>>>(hv, current, Ws1, bs1, vp);
    float* tpart = (float*)kA; // kA+vM contiguous = NT*HID*4 bytes
    k_mm<1, 0><<<GT, 256, 0, stream>>>(ht, wswA + (size_t)8 * 65536, nullptr, (void*)tpart, nullptr, NT);
    k_final<<<2048, 256, 0, stream>>>(tpart, vp, Ws2, bs2, (float*)d_out);
}

// Round 16
// 1213.983 us; speedup vs baseline: 1.5279x; 1.0244x over previous
//
#include <hip/hip_runtime.h>
#include <hip/hip_bf16.h>
#include <math.h>

#define HID 256
#define NH 8
#define DH 32
#define NL 2
#define NV 20000
#define NT 50000
#define NE 100000
#define NC 8
#define FIN 64

typedef unsigned short u16;
typedef unsigned int u32;
typedef short s16x8 __attribute__((ext_vector_type(8)));
typedef float f32x4 __attribute__((ext_vector_type(4)));

__device__ __forceinline__ float bf2f(u16 u) { return __uint_as_float(((u32)u) << 16); }
__device__ __forceinline__ u16 f2bf(float f) {
    u32 x = __float_as_uint(f);
    u32 r = ((x >> 16) & 1u) + 0x7fffu;
    return (u16)((x + r) >> 16);
}
__device__ __forceinline__ void up2(u32 u, float& a, float& b) {
    a = __uint_as_float(u << 16);
    b = __uint_as_float(u & 0xffff0000u);
}
__device__ __forceinline__ s16x8 gelu8(s16x8 a) {
    s16x8 r;
#pragma unroll
    for (int i = 0; i < 8; i++) {
        float v = bf2f((u16)a[i]);
        v = 0.5f * v * (1.f + erff(v * 0.70710678118654752f));
        r[i] = (short)f2bf(v);
    }
    return r;
}

// ---------------- zero fill ----------------
__global__ void k_zero_i(int* __restrict__ p, int n) {
    for (int i = blockIdx.x * 256 + threadIdx.x; i < n; i += gridDim.x * 256) p[i] = 0;
}

// ---------------- histogram of dst ----------------
__global__ void k_hist(const int* __restrict__ dst, int* __restrict__ cnt) {
    for (int e = blockIdx.x * 256 + threadIdx.x; e < NE; e += gridDim.x * 256)
        atomicAdd(&cnt[dst[e]], 1);
}

// ---------------- exclusive prefix scan ----------------
__global__ __launch_bounds__(1024) void k_scan(const int* __restrict__ cnt, int* __restrict__ rp, int n) {
    __shared__ int wsum[16];
    __shared__ int carry_s;
    int t = threadIdx.x, lane = t & 63, wv = t >> 6;
    if (t == 0) { carry_s = 0; rp[0] = 0; }
    __syncthreads();
    for (int base = 0; base < n; base += 1024) {
        int v = (base + t < n) ? cnt[base + t] : 0;
        int x = v;
#pragma unroll
        for (int off = 1; off < 64; off <<= 1) {
            int y = __shfl_up(x, off, 64);
            if (lane >= off) x += y;
        }
        if (lane == 63) wsum[wv] = x;
        __syncthreads();
        if (wv == 0 && lane < 16) {
            int s = wsum[lane];
#pragma unroll
            for (int off = 1; off < 16; off <<= 1) {
                int y = __shfl_up(s, off, 64);
                if (lane >= off) s += y;
            }
            wsum[lane] = s;
        }
        __syncthreads();
        int prefix = carry_s + (wv > 0 ? wsum[wv - 1] : 0);
        if (base + t < n) rp[base + t + 1] = prefix + x;
        __syncthreads();
        if (t == 0) carry_s += wsum[15];
        __syncthreads();
    }
}

// ---------------- copy int ----------------
__global__ void k_copy_i(const int* __restrict__ a, int* __restrict__ b, int n) {
    for (int i = blockIdx.x * 256 + threadIdx.x; i < n; i += gridDim.x * 256) b[i] = a[i];
}

// ---------------- scatter srcs into CSR slots ----------------
__global__ void k_scatter(const int* __restrict__ dst, const int* __restrict__ src,
                          int* __restrict__ fill, int* __restrict__ es) {
    for (int e = blockIdx.x * 256 + threadIdx.x; e < NE; e += gridDim.x * 256) {
        int d = dst[e];
        int p = atomicAdd(&fill[d], 1);
        es[p] = src[e];
    }
}

// ---------------- input projection ----------------
__global__ __launch_bounds__(256) void k_in_proj(const float* __restrict__ X, const float* __restrict__ W,
                          const float* __restrict__ b, u16* __restrict__ Y, int N) {
    const int NPB = 16;
    __shared__ float xs[NPB][FIN];
    int n0 = blockIdx.x * NPB;
    int t = threadIdx.x;
    for (int idx = t; idx < NPB * FIN; idx += 256) {
        int i = idx >> 6, c = idx & 63;
        int n = n0 + i;
        xs[i][c] = (n < N) ? X[(size_t)n * FIN + c] : 0.f;
    }
    __syncthreads();
    float acc[NPB];
#pragma unroll
    for (int i = 0; i < NPB; i++) acc[i] = 0.f;
    for (int c = 0; c < FIN; c++) {
        float w = W[c * HID + t];
#pragma unroll
        for (int i = 0; i < NPB; i++) acc[i] += xs[i][c] * w;
    }
    float bb = b[t];
    for (int i = 0; i < NPB; i++) {
        int n = n0 + i;
        if (n < N) Y[(size_t)n * HID + t] = f2bf(fmaxf(acc[i] + bb, 0.f));
    }
}

// swizzle index for MFMA B fragment: given (k,n) -> flat idx in Wsw
__device__ __forceinline__ int swz_idx(int k, int n) {
    int ks = k >> 5, r = k & 31;
    int j = r & 7;
    int l = ((r >> 3) << 4) | (n & 15);
    int nt = n >> 4;
    return ((ks * 16 + nt) * 64 + l) * 8 + j;
}

// ---------------- fuse rel matrix into projection weight, emit SWIZZLED bf16 ----------------
__global__ __launch_bounds__(256) void k_fuse_w(const float* __restrict__ W, const float* __restrict__ b,
                        const float* __restrict__ R, u16* __restrict__ Wsw, float* __restrict__ bout) {
    int h = blockIdx.x; // 8 blocks
    __shared__ float sR[DH * DH];
    int t = threadIdx.x;
    for (int idx = t; idx < DH * DH; idx += 256) sR[idx] = R[h * DH * DH + idx];
    __syncthreads();
    int f = t & 31, c0 = t >> 5;
    for (int c = c0; c < HID; c += 8) {
        float acc = 0.f;
#pragma unroll
        for (int d = 0; d < DH; d++) acc += W[c * HID + h * DH + d] * sR[d * DH + f];
        Wsw[swz_idx(c, h * DH + f)] = f2bf(acc);
    }
    if (t < DH) {
        float acc = 0.f;
#pragma unroll
        for (int d = 0; d < DH; d++) acc += b[h * DH + d] * sR[d * DH + t];
        bout[h * DH + t] = acc;
    }
}

// ---------------- batched swizzle of 9 static weights: Wq[0..3], Wa[0..3], Ws1 ----------------
__global__ __launch_bounds__(256) void k_swz_multi(const float* __restrict__ Wq, const float* __restrict__ Wa,
                                                   const float* __restrict__ Ws1, u16* __restrict__ out) {
    int slot = blockIdx.x >> 8;
    int idx = ((blockIdx.x & 255) << 8) | threadIdx.x; // 0..65535
    const float* src = (slot < 4) ? (Wq + (size_t)slot * 65536)
                     : (slot < 8) ? (Wa + (size_t)(slot - 4) * 65536)
                                  : Ws1;
    int j = idx & 7, l = (idx >> 3) & 63, nt = (idx >> 9) & 15, ks = idx >> 13;
    int k = ks * 32 + (l >> 4) * 8 + j;
    int n = nt * 16 + (l & 15);
    out[(size_t)slot * 65536 + idx] = f2bf(src[k * HID + n]);
}

// ---------------- MFMA GEMM, slim-wave: block = 16 rows x 256 cols, wave = 16x64 ----------------
// MODE 0: bf16 out. MODE 1: f32 out, no bias. MODE 2: skip-mix into Y(bf16). GELU: gelu(A) at load.
template <int MODE, int GELU>
__global__ __launch_bounds__(256) void k_mm(const u16* __restrict__ X, const u16* __restrict__ Wsw,
                                            const float* __restrict__ bias, void* __restrict__ Y,
                                            const float* __restrict__ skip_, int N) {
    int tid = threadIdx.x;
    int w = tid >> 6, lane = tid & 63;
    int r0 = blockIdx.x * 16;
    int rA = r0 + (lane & 15);
    int koffg = lane >> 4;
    s16x8 a[8];
    if (rA < N) {
        const s16x8* ap = (const s16x8*)(X + (size_t)rA * HID) + koffg;
#pragma unroll
        for (int ks = 0; ks < 8; ks++) a[ks] = ap[ks * 4];
    } else {
#pragma unroll
        for (int ks = 0; ks < 8; ks++) a[ks] = (s16x8){0, 0, 0, 0, 0, 0, 0, 0};
    }
    if (GELU) {
#pragma unroll
        for (int ks = 0; ks < 8; ks++) a[ks] = gelu8(a[ks]);
    }
    f32x4 acc[4];
#pragma unroll
    for (int nt = 0; nt < 4; nt++) acc[nt] = (f32x4){0.f, 0.f, 0.f, 0.f};
    const s16x8* wp = (const s16x8*)Wsw;
#pragma unroll
    for (int ks = 0; ks < 8; ks++) {
        const s16x8* wq = wp + (size_t)ks * 16 * 64 + lane;
#pragma unroll
        for (int nt = 0; nt < 4; nt++) {
            s16x8 b = wq[(w * 4 + nt) * 64];
            acc[nt] = __builtin_amdgcn_mfma_f32_16x16x32_bf16(a[ks], b, acc[nt], 0, 0, 0);
        }
    }
    int colb = lane & 15;
    int rowb = r0 + koffg * 4;
    float beta = 0.f, ombeta = 0.f;
    if (MODE == 2) { beta = 1.f / (1.f + expf(-skip_[0])); ombeta = 1.f - beta; }
#pragma unroll
    for (int nt = 0; nt < 4; nt++) {
        int col = w * 64 + nt * 16 + colb;
        float bb = (MODE == 1) ? 0.f : bias[col];
#pragma unroll
        for (int j = 0; j < 4; j++) {
            int row = rowb + j;
            if (row < N) {
                float v = acc[nt][j] + bb;
                if (MODE == 0) {
                    ((u16*)Y)[(size_t)row * HID + col] = f2bf(v);
                } else if (MODE == 1) {
                    ((float*)Y)[(size_t)row * HID + col] = v;
                } else {
                    u16* hp = (u16*)Y + (size_t)row * HID + col;
                    *hp = f2bf(beta * v + ombeta * bf2f(*hp));
                }
            }
        }
    }
}

// ---------------- dual-B slim-wave MFMA GEMM (A loaded once) ----------------
__global__ __launch_bounds__(256) void k_mm2(const u16* __restrict__ X,
                                             const u16* __restrict__ W1, const float* __restrict__ b1, u16* __restrict__ Y1,
                                             const u16* __restrict__ W2, const float* __restrict__ b2, u16* __restrict__ Y2,
                                             int N) {
    int tid = threadIdx.x;
    int w = tid >> 6, lane = tid & 63;
    int r0 = blockIdx.x * 16;
    int rA = r0 + (lane & 15);
    int koffg = lane >> 4;
    s16x8 a[8];
    if (rA < N) {
        const s16x8* ap = (const s16x8*)(X + (size_t)rA * HID) + koffg;
#pragma unroll
        for (int ks = 0; ks < 8; ks++) a[ks] = ap[ks * 4];
    } else {
#pragma unroll
        for (int ks = 0; ks < 8; ks++) a[ks] = (s16x8){0, 0, 0, 0, 0, 0, 0, 0};
    }
    int colb = lane & 15;
    int rowb = r0 + koffg * 4;
#pragma unroll
    for (int pass = 0; pass < 2; pass++) {
        const u16* Wsw = pass ? W2 : W1;
        const float* bias = pass ? b2 : b1;
        u16* Y = pass ? Y2 : Y1;
        f32x4 acc[4];
#pragma unroll
        for (int nt = 0; nt < 4; nt++) acc[nt] = (f32x4){0.f, 0.f, 0.f, 0.f};
        const s16x8* wp = (const s16x8*)Wsw;
#pragma unroll
        for (int ks = 0; ks < 8; ks++) {
            const s16x8* wq = wp + (size_t)ks * 16 * 64 + lane;
#pragma unroll
            for (int nt = 0; nt < 4; nt++) {
                s16x8 b = wq[(w * 4 + nt) * 64];
                acc[nt] = __builtin_amdgcn_mfma_f32_16x16x32_bf16(a[ks], b, acc[nt], 0, 0, 0);
            }
        }
#pragma unroll
        for (int nt = 0; nt < 4; nt++) {
            int col = w * 64 + nt * 16 + colb;
            float bb = bias[col];
#pragma unroll
            for (int j = 0; j < 4; j++) {
                int row = rowb + j;
                if (row < N) Y[(size_t)row * HID + col] = f2bf(acc[nt][j] + bb);
            }
        }
    }
}

// ---------------- triple-B slim-wave MFMA GEMM: q + k + v from one A read ----------------
__global__ __launch_bounds__(256) void k_mm3(const u16* __restrict__ X,
                                             const u16* __restrict__ W0, const float* __restrict__ b0, u16* __restrict__ Y0,
                                             const u16* __restrict__ W1, const float* __restrict__ b1, u16* __restrict__ Y1,
                                             const u16* __restrict__ W2, const float* __restrict__ b2, u16* __restrict__ Y2,
                                             int N) {
    int tid = threadIdx.x;
    int w = tid >> 6, lane = tid & 63;
    int r0 = blockIdx.x * 16;
    int rA = r0 + (lane & 15);
    int koffg = lane >> 4;
    s16x8 a[8];
    if (rA < N) {
        const s16x8* ap = (const s16x8*)(X + (size_t)rA * HID) + koffg;
#pragma unroll
        for (int ks = 0; ks < 8; ks++) a[ks] = ap[ks * 4];
    } else {
#pragma unroll
        for (int ks = 0; ks < 8; ks++) a[ks] = (s16x8){0, 0, 0, 0, 0, 0, 0, 0};
    }
    int colb = lane & 15;
    int rowb = r0 + koffg * 4;
#pragma unroll
    for (int pass = 0; pass < 3; pass++) {
        const u16* Wsw = (pass == 0) ? W0 : (pass == 1) ? W1 : W2;
        const float* bias = (pass == 0) ? b0 : (pass == 1) ? b1 : b2;
        u16* Y = (pass == 0) ? Y0 : (pass == 1) ? Y1 : Y2;
        f32x4 acc[4];
#pragma unroll
        for (int nt = 0; nt < 4; nt++) acc[nt] = (f32x4){0.f, 0.f, 0.f, 0.f};
        const s16x8* wp = (const s16x8*)Wsw;
#pragma unroll
        for (int ks = 0; ks < 8; ks++) {
            const s16x8* wq = wp + (size_t)ks * 16 * 64 + lane;
#pragma unroll
            for (int nt = 0; nt < 4; nt++) {
                s16x8 b = wq[(w * 4 + nt) * 64];
                acc[nt] = __builtin_amdgcn_mfma_f32_16x16x32_bf16(a[ks], b, acc[nt], 0, 0, 0);
            }
        }
#pragma unroll
        for (int nt = 0; nt < 4; nt++) {
            int col = w * 64 + nt * 16 + colb;
            float bb = bias[col];
#pragma unroll
            for (int j = 0; j < 4; j++) {
                int row = rowb + j;
                if (row < N) Y[(size_t)row * HID + col] = f2bf(acc[nt][j] + bb);
            }
        }
    }
}

// ---------------- per-dst-node online-softmax aggregation ----------------
__global__ __launch_bounds__(256) void k_node_attn(
        const u16* __restrict__ q, const u16* __restrict__ kA, const u16* __restrict__ vM,
        const int* __restrict__ rp, const int* __restrict__ es,
        const float* __restrict__ P, float scale,
        u16* __restrict__ agg, int Nd, int add) {
    int node = blockIdx.x * 4 + (threadIdx.x >> 6);
    if (node >= Nd) return;
    int lane = threadIdx.x & 63;
    int h = lane >> 3;
    float ph = P[h] * scale;
    uint2 qu = *(const uint2*)(q + (size_t)node * HID + lane * 4);
    float q0, q1, q2, q3; up2(qu.x, q0, q1); up2(qu.y, q2, q3);
    float m = -INFINITY, ss = 0.f, a0 = 0.f, a1 = 0.f, a2 = 0.f, a3 = 0.f;
    int jb = rp[node], je = rp[node + 1];
    for (int j = jb; j < je; j++) {
        int s = es[j];
        uint2 ku = *(const uint2*)(kA + (size_t)s * HID + lane * 4);
        float k0, k1, k2, k3; up2(ku.x, k0, k1); up2(ku.y, k2, k3);
        float part = q0 * k0 + q1 * k1 + q2 * k2 + q3 * k3;
        part += __shfl_xor(part, 1, 64);
        part += __shfl_xor(part, 2, 64);
        part += __shfl_xor(part, 4, 64);
        float logit = part * ph;
        float nm = fmaxf(m, logit);
        float corr = expf(m - nm);
        float ee = expf(logit - nm);
        uint2 vu = *(const uint2*)(vM + (size_t)s * HID + lane * 4);
        float v0, v1, v2, v3; up2(vu.x, v0, v1); up2(vu.y, v2, v3);
        ss = ss * corr + ee;
        a0 = a0 * corr + ee * v0; a1 = a1 * corr + ee * v1;
        a2 = a2 * corr + ee * v2; a3 = a3 * corr + ee * v3;
        m = nm;
    }
    float inv = 1.f / (ss + 1e-16f);
    a0 *= inv; a1 *= inv; a2 *= inv; a3 *= inv;
    u16* ap = agg + (size_t)node * HID + lane * 4;
    if (add) {
        a0 += bf2f(ap[0]); a1 += bf2f(ap[1]); a2 += bf2f(ap[2]); a3 += bf2f(ap[3]);
    }
    ap[0] = f2bf(a0); ap[1] = f2bf(a1); ap[2] = f2bf(a2); ap[3] = f2bf(a3);
}

// ---------------- vpart ----------------
__global__ void k_vpart(const u16* __restrict__ hv, const int* __restrict__ current,
                        const float* __restrict__ Ws1, const float* __restrict__ bs1,
                        float* __restrict__ vpart) {
    __shared__ float row[HID];
    int t = threadIdx.x;
    for (int c = 0; c < NC; c++) {
        int n = current[c * 2];
        row[t] = bf2f(hv[(size_t)n * HID + t]);
        __syncthreads();
        float acc = 0.f;
        for (int i = 0; i < HID; i++) acc += row[i] * Ws1[(size_t)(HID + i) * HID + t];
        vpart[c * HID + t] = acc + bs1[t];
        __syncthreads();
    }
}

// ---------------- final (R10-proven form) ----------------
__global__ __launch_bounds__(256) void k_final(const float* __restrict__ tpart, const float* __restrict__ vpart,
                        const float* __restrict__ Ws2, const float* __restrict__ bs2,
                        float* __restrict__ out) {
    __shared__ float vp[NC * HID];
    int t = threadIdx.x;
    for (int idx = t; idx < NC * HID; idx += 256) vp[idx] = vpart[idx];
    __syncthreads();
    int lane = t & 63, w = t >> 6;
    float w20[4], w21[4];
#pragma unroll
    for (int i = 0; i < 4; i++) {
        w20[i] = Ws2[(lane + 64 * i) * 2 + 0];
        w21[i] = Ws2[(lane + 64 * i) * 2 + 1];
    }
    float b0 = bs2[0], b1 = bs2[1];
    for (int n = blockIdx.x * 4 + w; n < NT; n += gridDim.x * 4) {
        float tp[4];
#pragma unroll
        for (int i = 0; i < 4; i++) tp[i] = tpart[(size_t)n * HID + lane + 64 * i];
#pragma unroll
        for (int c = 0; c < NC; c++) {
            float a0 = 0.f, a1 = 0.f;
#pragma unroll
            for (int i = 0; i < 4; i++) {
                float hm = fmaxf(tp[i] + vp[c * HID + lane + 64 * i], 0.f);
                a0 += hm * w20[i];
                a1 += hm * w21[i];
            }
#pragma unroll
            for (int off = 32; off >= 1; off >>= 1) {
                a0 += __shfl_xor(a0, off, 64);
                a1 += __shfl_xor(a1, off, 64);
            }
            if (lane == 0) {
                out[(size_t)c * NT + n] = a0 + b0;
                float z = a1 + b1;
                out[(size_t)NC * NT + (size_t)c * NT + n] = 1.f / (1.f + expf(-z));
            }
        }
    }
}

extern "C" void kernel_launch(void* const* d_in, const int* in_sizes, int n_in,
                              void* d_out, int out_size, void* d_ws, size_t ws_size,
                              hipStream_t stream) {
    (void)in_sizes; (void)n_in; (void)out_size;
    const float* x_v    = (const float*)d_in[0];
    const float* x_t    = (const float*)d_in[1];
    const int* ei_vt_s  = (const int*)d_in[2];
    const int* ei_vt_d  = (const int*)d_in[3];
    const int* ei_tv_s  = (const int*)d_in[4];
    const int* ei_tv_d  = (const int*)d_in[5];
    const int* ei_tt_s  = (const int*)d_in[6];
    const int* ei_tt_d  = (const int*)d_in[7];
    const int* current  = (const int*)d_in[8];
    const float* W_in_v = (const float*)d_in[9];
    const float* b_in_v = (const float*)d_in[10];
    const float* W_in_t = (const float*)d_in[11];
    const float* b_in_t = (const float*)d_in[12];
    const float* Wk     = (const float*)d_in[13];
    const float* bk     = (const float*)d_in[14];
    const float* Wq     = (const float*)d_in[15];
    const float* bq     = (const float*)d_in[16];
    const float* Wv     = (const float*)d_in[17];
    const float* bv     = (const float*)d_in[18];
    const float* Wa     = (const float*)d_in[19];
    const float* ba     = (const float*)d_in[20];
    const float* skip   = (const float*)d_in[21];
    const float* a_rel  = (const float*)d_in[22];
    const float* m_rel  = (const float*)d_in[23];
    const float* p_rel  = (const float*)d_in[24];
    const float* Ws1    = (const float*)d_in[25];
    const float* bs1    = (const float*)d_in[26];
    const float* Ws2    = (const float*)d_in[27];
    const float* bs2    = (const float*)d_in[28];

    char* p = (char*)d_ws;
    auto alloc = [&](size_t bytes) -> char* {
        char* r = p;
        p += (bytes + 255) & ~(size_t)255;
        return r;
    };
    u16* hv   = (u16*)alloc((size_t)NV * HID * 2);
    u16* ht   = (u16*)alloc((size_t)NT * HID * 2);
    u16* qb   = (u16*)alloc((size_t)NT * HID * 2);
    u16* qv   = (u16*)alloc((size_t)NV * HID * 2);
    u16* kA   = (u16*)alloc((size_t)NT * HID * 2); // kA+vM contiguous -> f32 tpart later
    u16* vM   = (u16*)alloc((size_t)NT * HID * 2);
    u16* kA0  = (u16*)alloc((size_t)NV * HID * 2);
    u16* vM0  = (u16*)alloc((size_t)NV * HID * 2);
    u16* agg  = (u16*)alloc((size_t)NT * HID * 2);
    int* rp_vt = (int*)alloc((size_t)(NT + 1) * 4);
    int* rp_tv = (int*)alloc((size_t)(NV + 1) * 4);
    int* rp_tt = (int*)alloc((size_t)(NT + 1) * 4);
    int* es_vt = (int*)alloc((size_t)NE * 4);
    int* es_tv = (int*)alloc((size_t)NE * 4);
    int* es_tt = (int*)alloc((size_t)NE * 4);
    int* cnt   = (int*)alloc((size_t)NT * 4);
    int* fill  = (int*)alloc((size_t)NT * 4);
    float* vp  = (float*)alloc((size_t)NC * HID * 4);
    float* bkF = (float*)alloc(HID * 4);
    float* bvF = (float*)alloc(HID * 4);
    u16*  wswK = (u16*)alloc((size_t)HID * HID * 2);
    u16*  wswV = (u16*)alloc((size_t)HID * HID * 2);
    u16*  wswA = (u16*)alloc((size_t)9 * HID * HID * 2);
    if ((size_t)(p - (char*)d_ws) > ws_size) return; // clean fail -> zeros signature

    const float scale = 0.17677669529663687f;

    // ---- build 3 CSRs ----
    {
        const int* DL[3] = { ei_vt_d, ei_tv_d, ei_tt_d };
        const int* SL[3] = { ei_vt_s, ei_tv_s, ei_tt_s };
        int* RP[3] = { rp_vt, rp_tv, rp_tt };
        int* ES[3] = { es_vt, es_tv, es_tt };
        int ND[3] = { NT, NV, NT };
        for (int r = 0; r < 3; r++) {
            k_zero_i<<<256, 256, 0, stream>>>(cnt, ND[r]);
            k_hist<<<512, 256, 0, stream>>>(DL[r], cnt);
            k_scan<<<1, 1024, 0, stream>>>(cnt, RP[r], ND[r]);
            k_copy_i<<<256, 256, 0, stream>>>(RP[r], fill, ND[r]);
            k_scatter<<<512, 256, 0, stream>>>(DL[r], SL[r], fill, ES[r]);
        }
    }

    // ---- swizzle all static weights in one launch ----
    k_swz_multi<<<9 * 256, 256, 0, stream>>>(Wq, Wa, Ws1, wswA);

    k_in_proj<<<(NV + 15) / 16, 256, 0, stream>>>(x_v, W_in_v, b_in_v, hv, NV);
    k_in_proj<<<(NT + 15) / 16, 256, 0, stream>>>(x_t, W_in_t, b_in_t, ht, NT);

    const int GV = (NV + 15) / 16, GT = (NT + 15) / 16;

    for (int l = 0; l < NL; l++) {
        const float* Wk0 = Wk + (size_t)(l * 2 + 0) * HID * HID;
        const float* Wk1 = Wk + (size_t)(l * 2 + 1) * HID * HID;
        const float* bk0 = bk + (l * 2 + 0) * HID, *bk1 = bk + (l * 2 + 1) * HID;
        const float* Wv0 = Wv + (size_t)(l * 2 + 0) * HID * HID;
        const float* Wv1 = Wv + (size_t)(l * 2 + 1) * HID * HID;
        const float* bv0 = bv + (l * 2 + 0) * HID, *bv1 = bv + (l * 2 + 1) * HID;
        const float* bq0 = bq + (l * 2 + 0) * HID, *bq1 = bq + (l * 2 + 1) * HID;
        const u16* WqS0 = wswA + (size_t)(l * 2 + 0) * 65536;
        const u16* WqS1 = wswA + (size_t)(l * 2 + 1) * 65536;
        const u16* WaS0 = wswA + (size_t)(4 + l * 2 + 0) * 65536;
        const u16* WaS1 = wswA + (size_t)(4 + l * 2 + 1) * 65536;
        const float* A0 = a_rel + (size_t)(l * 3 + 0) * NH * DH * DH;
        const float* A1 = a_rel + (size_t)(l * 3 + 1) * NH * DH * DH;
        const float* A2 = a_rel + (size_t)(l * 3 + 2) * NH * DH * DH;
        const float* M0 = m_rel + (size_t)(l * 3 + 0) * NH * DH * DH;
        const float* M1 = m_rel + (size_t)(l * 3 + 1) * NH * DH * DH;
        const float* M2 = m_rel + (size_t)(l * 3 + 2) * NH * DH * DH;
        const float* P0 = p_rel + (size_t)(l * 3 + 0) * NH;
        const float* P1 = p_rel + (size_t)(l * 3 + 1) * NH;
        const float* P2 = p_rel + (size_t)(l * 3 + 2) * NH;

        // A. r0 (v->t) weights; fused q_v + k0 + v0 from OLD hv (one A read)
        k_fuse_w<<<NH, 256, 0, stream>>>(Wk0, bk0, A0, wswK, bkF);
        k_fuse_w<<<NH, 256, 0, stream>>>(Wv0, bv0, M0, wswV, bvF);
        k_mm3<<<GV, 256, 0, stream>>>(hv, WqS0, bq0, qv, wswK, bkF, kA0, wswV, bvF, vM0, NV);

        // B. r1 (t->v) weights; fused q_t + k1 + v1 from OLD ht (one A read)
        k_fuse_w<<<NH, 256, 0, stream>>>(Wk1, bk1, A1, wswK, bkF);
        k_fuse_w<<<NH, 256, 0, stream>>>(Wv1, bv1, M1, wswV, bvF);
        k_mm3<<<GT, 256, 0, stream>>>(ht, WqS1, bq1, qb, wswK, bkF, kA, wswV, bvF, vM, NT);

        // C. aggregate r1 into agg (dst = v)
        k_node_attn<<<(NV + 3) / 4, 256, 0, stream>>>(qv, kA, vM, rp_tv, es_tv, P1, scale, agg, NV, 0);

        // D. update hv (old hv fully consumed)
        k_mm<2, 1><<<GV, 256, 0, stream>>>(agg, WaS0, ba + (l * 2 + 0) * HID, hv, skip + (l * 2 + 0), NV);

        // E. aggregate r0 into agg (dst = t, overwrite)
        k_node_attn<<<(NT + 3) / 4, 256, 0, stream>>>(qb, kA0, vM0, rp_vt, es_vt, P0, scale, agg, NT, 0);

        // F. r2 (t->t): k/v from OLD ht (still pre-update); aggregate (add)
        k_fuse_w<<<NH, 256, 0, stream>>>(Wk1, bk1, A2, wswK, bkF);
        k_fuse_w<<<NH, 256, 0, stream>>>(Wv1, bv1, M2, wswV, bvF);
        k_mm2<<<GT, 256, 0, stream>>>(ht, wswK, bkF, kA, wswV, bvF, vM, NT);
        k_node_attn<<<(NT + 3) / 4, 256, 0, stream>>>(qb, kA, vM, rp_tt, es_tt, P2, scale, agg, NT, 1);

        // G. update ht
        k_mm<2, 1><<<GT, 256, 0, stream>>>(agg, WaS1, ba + (l * 2 + 1) * HID, ht, skip + (l * 2 + 1), NT);
    }

    k_vpart<<<1, 256, 0, stream>>>(hv, current, Ws1, bs1, vp);
    float* tpart = (float*)kA; // kA+vM contiguous = NT*HID*4 bytes
    k_mm<1, 0><<<GT, 256, 0, stream>>>(ht, wswA + (size_t)8 * 65536, nullptr, (void*)tpart, nullptr, NT);
    k_final<<<2048, 256, 0, stream>>>(tpart, vp, Ws2, bs2, (float*)d_out);
}

// Round 17
// 1176.561 us; speedup vs baseline: 1.5765x; 1.0318x over previous
//
#include <hip/hip_runtime.h>
#include <hip/hip_bf16.h>
#include <math.h>

#define HID 256
#define NH 8
#define DH 32
#define NL 2
#define NV 20000
#define NT 50000
#define NE 100000
#define NC 8
#define FIN 64

typedef unsigned short u16;
typedef unsigned int u32;
typedef short s16x8 __attribute__((ext_vector_type(8)));
typedef float f32x4 __attribute__((ext_vector_type(4)));

__device__ __forceinline__ float bf2f(u16 u) { return __uint_as_float(((u32)u) << 16); }
__device__ __forceinline__ u16 f2bf(float f) {
    u32 x = __float_as_uint(f);
    u32 r = ((x >> 16) & 1u) + 0x7fffu;
    return (u16)((x + r) >> 16);
}
__device__ __forceinline__ void up2(u32 u, float& a, float& b) {
    a = __uint_as_float(u << 16);
    b = __uint_as_float(u & 0xffff0000u);
}
__device__ __forceinline__ s16x8 gelu8(s16x8 a) {
    s16x8 r;
#pragma unroll
    for (int i = 0; i < 8; i++) {
        float v = bf2f((u16)a[i]);
        v = 0.5f * v * (1.f + erff(v * 0.70710678118654752f));
        r[i] = (short)f2bf(v);
    }
    return r;
}

// ---------------- zero fill ----------------
__global__ void k_zero_i(int* __restrict__ p, int n) {
    for (int i = blockIdx.x * 256 + threadIdx.x; i < n; i += gridDim.x * 256) p[i] = 0;
}

// ---------------- histogram of dst ----------------
__global__ void k_hist(const int* __restrict__ dst, int* __restrict__ cnt) {
    for (int e = blockIdx.x * 256 + threadIdx.x; e < NE; e += gridDim.x * 256)
        atomicAdd(&cnt[dst[e]], 1);
}

// ---------------- exclusive prefix scan ----------------
__global__ __launch_bounds__(1024) void k_scan(const int* __restrict__ cnt, int* __restrict__ rp, int n) {
    __shared__ int wsum[16];
    __shared__ int carry_s;
    int t = threadIdx.x, lane = t & 63, wv = t >> 6;
    if (t == 0) { carry_s = 0; rp[0] = 0; }
    __syncthreads();
    for (int base = 0; base < n; base += 1024) {
        int v = (base + t < n) ? cnt[base + t] : 0;
        int x = v;
#pragma unroll
        for (int off = 1; off < 64; off <<= 1) {
            int y = __shfl_up(x, off, 64);
            if (lane >= off) x += y;
        }
        if (lane == 63) wsum[wv] = x;
        __syncthreads();
        if (wv == 0 && lane < 16) {
            int s = wsum[lane];
#pragma unroll
            for (int off = 1; off < 16; off <<= 1) {
                int y = __shfl_up(s, off, 64);
                if (lane >= off) s += y;
            }
            wsum[lane] = s;
        }
        __syncthreads();
        int prefix = carry_s + (wv > 0 ? wsum[wv - 1] : 0);
        if (base + t < n) rp[base + t + 1] = prefix + x;
        __syncthreads();
        if (t == 0) carry_s += wsum[15];
        __syncthreads();
    }
}

// ---------------- copy int ----------------
__global__ void k_copy_i(const int* __restrict__ a, int* __restrict__ b, int n) {
    for (int i = blockIdx.x * 256 + threadIdx.x; i < n; i += gridDim.x * 256) b[i] = a[i];
}

// ---------------- scatter srcs into CSR slots ----------------
__global__ void k_scatter(const int* __restrict__ dst, const int* __restrict__ src,
                          int* __restrict__ fill, int* __restrict__ es) {
    for (int e = blockIdx.x * 256 + threadIdx.x; e < NE; e += gridDim.x * 256) {
        int d = dst[e];
        int p = atomicAdd(&fill[d], 1);
        es[p] = src[e];
    }
}

// ---------------- input projection ----------------
__global__ __launch_bounds__(256) void k_in_proj(const float* __restrict__ X, const float* __restrict__ W,
                          const float* __restrict__ b, u16* __restrict__ Y, int N) {
    const int NPB = 16;
    __shared__ float xs[NPB][FIN];
    int n0 = blockIdx.x * NPB;
    int t = threadIdx.x;
    for (int idx = t; idx < NPB * FIN; idx += 256) {
        int i = idx >> 6, c = idx & 63;
        int n = n0 + i;
        xs[i][c] = (n < N) ? X[(size_t)n * FIN + c] : 0.f;
    }
    __syncthreads();
    float acc[NPB];
#pragma unroll
    for (int i = 0; i < NPB; i++) acc[i] = 0.f;
    for (int c = 0; c < FIN; c++) {
        float w = W[c * HID + t];
#pragma unroll
        for (int i = 0; i < NPB; i++) acc[i] += xs[i][c] * w;
    }
    float bb = b[t];
    for (int i = 0; i < NPB; i++) {
        int n = n0 + i;
        if (n < N) Y[(size_t)n * HID + t] = f2bf(fmaxf(acc[i] + bb, 0.f));
    }
}

// swizzle index for MFMA B fragment: given (k,n) -> flat idx in Wsw
__device__ __forceinline__ int swz_idx(int k, int n) {
    int ks = k >> 5, r = k & 31;
    int j = r & 7;
    int l = ((r >> 3) << 4) | (n & 15);
    int nt = n >> 4;
    return ((ks * 16 + nt) * 64 + l) * 8 + j;
}

// ---------------- fuse rel matrix into projection weight, emit SWIZZLED bf16 ----------------
__global__ __launch_bounds__(256) void k_fuse_w(const float* __restrict__ W, const float* __restrict__ b,
                        const float* __restrict__ R, u16* __restrict__ Wsw, float* __restrict__ bout) {
    int h = blockIdx.x; // 8 blocks
    __shared__ float sR[DH * DH];
    int t = threadIdx.x;
    for (int idx = t; idx < DH * DH; idx += 256) sR[idx] = R[h * DH * DH + idx];
    __syncthreads();
    int f = t & 31, c0 = t >> 5;
    for (int c = c0; c < HID; c += 8) {
        float acc = 0.f;
#pragma unroll
        for (int d = 0; d < DH; d++) acc += W[c * HID + h * DH + d] * sR[d * DH + f];
        Wsw[swz_idx(c, h * DH + f)] = f2bf(acc);
    }
    if (t < DH) {
        float acc = 0.f;
#pragma unroll
        for (int d = 0; d < DH; d++) acc += b[h * DH + d] * sR[d * DH + t];
        bout[h * DH + t] = acc;
    }
}

// ---------------- batched swizzle of 9 static weights: Wq[0..3], Wa[0..3], Ws1 ----------------
__global__ __launch_bounds__(256) void k_swz_multi(const float* __restrict__ Wq, const float* __restrict__ Wa,
                                                   const float* __restrict__ Ws1, u16* __restrict__ out) {
    int slot = blockIdx.x >> 8;
    int idx = ((blockIdx.x & 255) << 8) | threadIdx.x; // 0..65535
    const float* src = (slot < 4) ? (Wq + (size_t)slot * 65536)
                     : (slot < 8) ? (Wa + (size_t)(slot - 4) * 65536)
                                  : Ws1;
    int j = idx & 7, l = (idx >> 3) & 63, nt = (idx >> 9) & 15, ks = idx >> 13;
    int k = ks * 32 + (l >> 4) * 8 + j;
    int n = nt * 16 + (l & 15);
    out[(size_t)slot * 65536 + idx] = f2bf(src[k * HID + n]);
}

// ---------------- MFMA GEMM, slim-wave ----------------
template <int MODE, int GELU>
__global__ __launch_bounds__(256) void k_mm(const u16* __restrict__ X, const u16* __restrict__ Wsw,
                                            const float* __restrict__ bias, void* __restrict__ Y,
                                            const float* __restrict__ skip_, int N) {
    int tid = threadIdx.x;
    int w = tid >> 6, lane = tid & 63;
    int r0 = blockIdx.x * 16;
    int rA = r0 + (lane & 15);
    int koffg = lane >> 4;
    s16x8 a[8];
    if (rA < N) {
        const s16x8* ap = (const s16x8*)(X + (size_t)rA * HID) + koffg;
#pragma unroll
        for (int ks = 0; ks < 8; ks++) a[ks] = ap[ks * 4];
    } else {
#pragma unroll
        for (int ks = 0; ks < 8; ks++) a[ks] = (s16x8){0, 0, 0, 0, 0, 0, 0, 0};
    }
    if (GELU) {
#pragma unroll
        for (int ks = 0; ks < 8; ks++) a[ks] = gelu8(a[ks]);
    }
    f32x4 acc[4];
#pragma unroll
    for (int nt = 0; nt < 4; nt++) acc[nt] = (f32x4){0.f, 0.f, 0.f, 0.f};
    const s16x8* wp = (const s16x8*)Wsw;
#pragma unroll
    for (int ks = 0; ks < 8; ks++) {
        const s16x8* wq = wp + (size_t)ks * 16 * 64 + lane;
#pragma unroll
        for (int nt = 0; nt < 4; nt++) {
            s16x8 b = wq[(w * 4 + nt) * 64];
            acc[nt] = __builtin_amdgcn_mfma_f32_16x16x32_bf16(a[ks], b, acc[nt], 0, 0, 0);
        }
    }
    int colb = lane & 15;
    int rowb = r0 + koffg * 4;
    float beta = 0.f, ombeta = 0.f;
    if (MODE == 2) { beta = 1.f / (1.f + expf(-skip_[0])); ombeta = 1.f - beta; }
#pragma unroll
    for (int nt = 0; nt < 4; nt++) {
        int col = w * 64 + nt * 16 + colb;
        float bb = (MODE == 1) ? 0.f : bias[col];
#pragma unroll
        for (int j = 0; j < 4; j++) {
            int row = rowb + j;
            if (row < N) {
                float v = acc[nt][j] + bb;
                if (MODE == 0) {
                    ((u16*)Y)[(size_t)row * HID + col] = f2bf(v);
                } else if (MODE == 1) {
                    ((float*)Y)[(size_t)row * HID + col] = v;
                } else {
                    u16* hp = (u16*)Y + (size_t)row * HID + col;
                    *hp = f2bf(beta * v + ombeta * bf2f(*hp));
                }
            }
        }
    }
}

// ---------------- dual-B slim-wave MFMA GEMM (A loaded once) ----------------
__global__ __launch_bounds__(256) void k_mm2(const u16* __restrict__ X,
                                             const u16* __restrict__ W1, const float* __restrict__ b1, u16* __restrict__ Y1,
                                             const u16* __restrict__ W2, const float* __restrict__ b2, u16* __restrict__ Y2,
                                             int N) {
    int tid = threadIdx.x;
    int w = tid >> 6, lane = tid & 63;
    int r0 = blockIdx.x * 16;
    int rA = r0 + (lane & 15);
    int koffg = lane >> 4;
    s16x8 a[8];
    if (rA < N) {
        const s16x8* ap = (const s16x8*)(X + (size_t)rA * HID) + koffg;
#pragma unroll
        for (int ks = 0; ks < 8; ks++) a[ks] = ap[ks * 4];
    } else {
#pragma unroll
        for (int ks = 0; ks < 8; ks++) a[ks] = (s16x8){0, 0, 0, 0, 0, 0, 0, 0};
    }
    int colb = lane & 15;
    int rowb = r0 + koffg * 4;
#pragma unroll
    for (int pass = 0; pass < 2; pass++) {
        const u16* Wsw = pass ? W2 : W1;
        const float* bias = pass ? b2 : b1;
        u16* Y = pass ? Y2 : Y1;
        f32x4 acc[4];
#pragma unroll
        for (int nt = 0; nt < 4; nt++) acc[nt] = (f32x4){0.f, 0.f, 0.f, 0.f};
        const s16x8* wp = (const s16x8*)Wsw;
#pragma unroll
        for (int ks = 0; ks < 8; ks++) {
            const s16x8* wq = wp + (size_t)ks * 16 * 64 + lane;
#pragma unroll
            for (int nt = 0; nt < 4; nt++) {
                s16x8 b = wq[(w * 4 + nt) * 64];
                acc[nt] = __builtin_amdgcn_mfma_f32_16x16x32_bf16(a[ks], b, acc[nt], 0, 0, 0);
            }
        }
#pragma unroll
        for (int nt = 0; nt < 4; nt++) {
            int col = w * 64 + nt * 16 + colb;
            float bb = bias[col];
#pragma unroll
            for (int j = 0; j < 4; j++) {
                int row = rowb + j;
                if (row < N) Y[(size_t)row * HID + col] = f2bf(acc[nt][j] + bb);
            }
        }
    }
}

// ---------------- triple-B slim-wave MFMA GEMM: q + k + v from one A read ----------------
__global__ __launch_bounds__(256) void k_mm3(const u16* __restrict__ X,
                                             const u16* __restrict__ W0, const float* __restrict__ b0, u16* __restrict__ Y0,
                                             const u16* __restrict__ W1, const float* __restrict__ b1, u16* __restrict__ Y1,
                                             const u16* __restrict__ W2, const float* __restrict__ b2, u16* __restrict__ Y2,
                                             int N) {
    int tid = threadIdx.x;
    int w = tid >> 6, lane = tid & 63;
    int r0 = blockIdx.x * 16;
    int rA = r0 + (lane & 15);
    int koffg = lane >> 4;
    s16x8 a[8];
    if (rA < N) {
        const s16x8* ap = (const s16x8*)(X + (size_t)rA * HID) + koffg;
#pragma unroll
        for (int ks = 0; ks < 8; ks++) a[ks] = ap[ks * 4];
    } else {
#pragma unroll
        for (int ks = 0; ks < 8; ks++) a[ks] = (s16x8){0, 0, 0, 0, 0, 0, 0, 0};
    }
    int colb = lane & 15;
    int rowb = r0 + koffg * 4;
#pragma unroll
    for (int pass = 0; pass < 3; pass++) {
        const u16* Wsw = (pass == 0) ? W0 : (pass == 1) ? W1 : W2;
        const float* bias = (pass == 0) ? b0 : (pass == 1) ? b1 : b2;
        u16* Y = (pass == 0) ? Y0 : (pass == 1) ? Y1 : Y2;
        f32x4 acc[4];
#pragma unroll
        for (int nt = 0; nt < 4; nt++) acc[nt] = (f32x4){0.f, 0.f, 0.f, 0.f};
        const s16x8* wp = (const s16x8*)Wsw;
#pragma unroll
        for (int ks = 0; ks < 8; ks++) {
            const s16x8* wq = wp + (size_t)ks * 16 * 64 + lane;
#pragma unroll
            for (int nt = 0; nt < 4; nt++) {
                s16x8 b = wq[(w * 4 + nt) * 64];
                acc[nt] = __builtin_amdgcn_mfma_f32_16x16x32_bf16(a[ks], b, acc[nt], 0, 0, 0);
            }
        }
#pragma unroll
        for (int nt = 0; nt < 4; nt++) {
            int col = w * 64 + nt * 16 + colb;
            float bb = bias[col];
#pragma unroll
            for (int j = 0; j < 4; j++) {
                int row = rowb + j;
                if (row < N) Y[(size_t)row * HID + col] = f2bf(acc[nt][j] + bb);
            }
        }
    }
}

// ---------------- online-softmax over one CSR with 1-edge-deep prefetch ----------------
// Accumulates relation output (normalized) into o0..o3. Returns nothing else.
__device__ __forceinline__ void attn_pass(const u16* __restrict__ kA, const u16* __restrict__ vM,
                                          const int* __restrict__ es, int jb, int je,
                                          float q0, float q1, float q2, float q3, float ph, int lane4,
                                          float& o0, float& o1, float& o2, float& o3) {
    float m = -INFINITY, ss = 0.f, a0 = 0.f, a1 = 0.f, a2 = 0.f, a3 = 0.f;
    uint2 kuN = {0, 0}, vuN = {0, 0};
    if (jb < je) {
        int s0 = es[jb];
        kuN = *(const uint2*)(kA + (size_t)s0 * HID + lane4);
        vuN = *(const uint2*)(vM + (size_t)s0 * HID + lane4);
    }
    for (int j = jb; j < je; j++) {
        uint2 ku = kuN, vu = vuN;
        if (j + 1 < je) {
            int s1 = es[j + 1];
            kuN = *(const uint2*)(kA + (size_t)s1 * HID + lane4);
            vuN = *(const uint2*)(vM + (size_t)s1 * HID + lane4);
        }
        float k0, k1, k2, k3; up2(ku.x, k0, k1); up2(ku.y, k2, k3);
        float part = q0 * k0 + q1 * k1 + q2 * k2 + q3 * k3;
        part += __shfl_xor(part, 1, 64);
        part += __shfl_xor(part, 2, 64);
        part += __shfl_xor(part, 4, 64);
        float logit = part * ph;
        float nm = fmaxf(m, logit);
        float corr = expf(m - nm);
        float ee = expf(logit - nm);
        float v0, v1, v2, v3; up2(vu.x, v0, v1); up2(vu.y, v2, v3);
        ss = ss * corr + ee;
        a0 = a0 * corr + ee * v0; a1 = a1 * corr + ee * v1;
        a2 = a2 * corr + ee * v2; a3 = a3 * corr + ee * v3;
        m = nm;
    }
    float inv = 1.f / (ss + 1e-16f);
    o0 += a0 * inv; o1 += a1 * inv; o2 += a2 * inv; o3 += a3 * inv;
}

// ---------------- single-relation node attention ----------------
__global__ __launch_bounds__(256) void k_node_attn(
        const u16* __restrict__ q, const u16* __restrict__ kA, const u16* __restrict__ vM,
        const int* __restrict__ rp, const int* __restrict__ es,
        const float* __restrict__ P, float scale,
        u16* __restrict__ agg, int Nd) {
    int node = blockIdx.x * 4 + (threadIdx.x >> 6);
    if (node >= Nd) return;
    int lane = threadIdx.x & 63;
    float ph = P[lane >> 3] * scale;
    uint2 qu = *(const uint2*)(q + (size_t)node * HID + lane * 4);
    float q0, q1, q2, q3; up2(qu.x, q0, q1); up2(qu.y, q2, q3);
    float o0 = 0.f, o1 = 0.f, o2 = 0.f, o3 = 0.f;
    attn_pass(kA, vM, es, rp[node], rp[node + 1], q0, q1, q2, q3, ph, lane * 4, o0, o1, o2, o3);
    u16* ap = agg + (size_t)node * HID + lane * 4;
    ap[0] = f2bf(o0); ap[1] = f2bf(o1); ap[2] = f2bf(o2); ap[3] = f2bf(o3);
}

// ---------------- dual-relation node attention (dst=t: r0 + r2 summed in f32) ----------------
__global__ __launch_bounds__(256) void k_node_attn2(
        const u16* __restrict__ q,
        const u16* __restrict__ kA0, const u16* __restrict__ vM0,
        const int* __restrict__ rp0, const int* __restrict__ es0, const float* __restrict__ P0,
        const u16* __restrict__ kA1, const u16* __restrict__ vM1,
        const int* __restrict__ rp1, const int* __restrict__ es1, const float* __restrict__ P1,
        float scale, u16* __restrict__ agg, int Nd) {
    int node = blockIdx.x * 4 + (threadIdx.x >> 6);
    if (node >= Nd) return;
    int lane = threadIdx.x & 63;
    int h = lane >> 3;
    float ph0 = P0[h] * scale, ph1 = P1[h] * scale;
    uint2 qu = *(const uint2*)(q + (size_t)node * HID + lane * 4);
    float q0, q1, q2, q3; up2(qu.x, q0, q1); up2(qu.y, q2, q3);
    float o0 = 0.f, o1 = 0.f, o2 = 0.f, o3 = 0.f;
    attn_pass(kA0, vM0, es0, rp0[node], rp0[node + 1], q0, q1, q2, q3, ph0, lane * 4, o0, o1, o2, o3);
    attn_pass(kA1, vM1, es1, rp1[node], rp1[node + 1], q0, q1, q2, q3, ph1, lane * 4, o0, o1, o2, o3);
    u16* ap = agg + (size_t)node * HID + lane * 4;
    ap[0] = f2bf(o0); ap[1] = f2bf(o1); ap[2] = f2bf(o2); ap[3] = f2bf(o3);
}

// ---------------- vpart ----------------
__global__ void k_vpart(const u16* __restrict__ hv, const int* __restrict__ current,
                        const float* __restrict__ Ws1, const float* __restrict__ bs1,
                        float* __restrict__ vpart) {
    __shared__ float row[HID];
    int t = threadIdx.x;
    for (int c = 0; c < NC; c++) {
        int n = current[c * 2];
        row[t] = bf2f(hv[(size_t)n * HID + t]);
        __syncthreads();
        float acc = 0.f;
        for (int i = 0; i < HID; i++) acc += row[i] * Ws1[(size_t)(HID + i) * HID + t];
        vpart[c * HID + t] = acc + bs1[t];
        __syncthreads();
    }
}

// ---------------- final (R10-proven form) ----------------
__global__ __launch_bounds__(256) void k_final(const float* __restrict__ tpart, const float* __restrict__ vpart,
                        const float* __restrict__ Ws2, const float* __restrict__ bs2,
                        float* __restrict__ out) {
    __shared__ float vp[NC * HID];
    int t = threadIdx.x;
    for (int idx = t; idx < NC * HID; idx += 256) vp[idx] = vpart[idx];
    __syncthreads();
    int lane = t & 63, w = t >> 6;
    float w20[4], w21[4];
#pragma unroll
    for (int i = 0; i < 4; i++) {
        w20[i] = Ws2[(lane + 64 * i) * 2 + 0];
        w21[i] = Ws2[(lane + 64 * i) * 2 + 1];
    }
    float b0 = bs2[0], b1 = bs2[1];
    for (int n = blockIdx.x * 4 + w; n < NT; n += gridDim.x * 4) {
        float tp[4];
#pragma unroll
        for (int i = 0; i < 4; i++) tp[i] = tpart[(size_t)n * HID + lane + 64 * i];
#pragma unroll
        for (int c = 0; c < NC; c++) {
            float a0 = 0.f, a1 = 0.f;
#pragma unroll
            for (int i = 0; i < 4; i++) {
                float hm = fmaxf(tp[i] + vp[c * HID + lane + 64 * i], 0.f);
                a0 += hm * w20[i];
                a1 += hm * w21[i];
            }
#pragma unroll
            for (int off = 32; off >= 1; off >>= 1) {
                a0 += __shfl_xor(a0, off, 64);
                a1 += __shfl_xor(a1, off, 64);
            }
            if (lane == 0) {
                out[(size_t)c * NT + n] = a0 + b0;
                float z = a1 + b1;
                out[(size_t)NC * NT + (size_t)c * NT + n] = 1.f / (1.f + expf(-z));
            }
        }
    }
}

extern "C" void kernel_launch(void* const* d_in, const int* in_sizes, int n_in,
                              void* d_out, int out_size, void* d_ws, size_t ws_size,
                              hipStream_t stream) {
    (void)in_sizes; (void)n_in; (void)out_size;
    const float* x_v    = (const float*)d_in[0];
    const float* x_t    = (const float*)d_in[1];
    const int* ei_vt_s  = (const int*)d_in[2];
    const int* ei_vt_d  = (const int*)d_in[3];
    const int* ei_tv_s  = (const int*)d_in[4];
    const int* ei_tv_d  = (const int*)d_in[5];
    const int* ei_tt_s  = (const int*)d_in[6];
    const int* ei_tt_d  = (const int*)d_in[7];
    const int* current  = (const int*)d_in[8];
    const float* W_in_v = (const float*)d_in[9];
    const float* b_in_v = (const float*)d_in[10];
    const float* W_in_t = (const float*)d_in[11];
    const float* b_in_t = (const float*)d_in[12];
    const float* Wk     = (const float*)d_in[13];
    const float* bk     = (const float*)d_in[14];
    const float* Wq     = (const float*)d_in[15];
    const float* bq     = (const float*)d_in[16];
    const float* Wv     = (const float*)d_in[17];
    const float* bv     = (const float*)d_in[18];
    const float* Wa     = (const float*)d_in[19];
    const float* ba     = (const float*)d_in[20];
    const float* skip   = (const float*)d_in[21];
    const float* a_rel  = (const float*)d_in[22];
    const float* m_rel  = (const float*)d_in[23];
    const float* p_rel  = (const float*)d_in[24];
    const float* Ws1    = (const float*)d_in[25];
    const float* bs1    = (const float*)d_in[26];
    const float* Ws2    = (const float*)d_in[27];
    const float* bs2    = (const float*)d_in[28];

    char* p = (char*)d_ws;
    auto alloc = [&](size_t bytes) -> char* {
        char* r = p;
        p += (bytes + 255) & ~(size_t)255;
        return r;
    };
    u16* hv   = (u16*)alloc((size_t)NV * HID * 2);
    u16* ht   = (u16*)alloc((size_t)NT * HID * 2);
    u16* qb   = (u16*)alloc((size_t)NT * HID * 2);
    u16* qv   = (u16*)alloc((size_t)NV * HID * 2);
    u16* kA   = (u16*)alloc((size_t)NT * HID * 2); // kA+vM contiguous -> f32 tpart later
    u16* vM   = (u16*)alloc((size_t)NT * HID * 2);
    u16* kA0  = (u16*)alloc((size_t)NV * HID * 2);
    u16* vM0  = (u16*)alloc((size_t)NV * HID * 2);
    u16* agg  = (u16*)alloc((size_t)NT * HID * 2);
    int* rp_vt = (int*)alloc((size_t)(NT + 1) * 4);
    int* rp_tv = (int*)alloc((size_t)(NV + 1) * 4);
    int* rp_tt = (int*)alloc((size_t)(NT + 1) * 4);
    int* es_vt = (int*)alloc((size_t)NE * 4);
    int* es_tv = (int*)alloc((size_t)NE * 4);
    int* es_tt = (int*)alloc((size_t)NE * 4);
    int* cnt   = (int*)alloc((size_t)NT * 4);
    int* fill  = (int*)alloc((size_t)NT * 4);
    float* vp  = (float*)alloc((size_t)NC * HID * 4);
    float* bkF = (float*)alloc(HID * 4);
    float* bvF = (float*)alloc(HID * 4);
    u16*  wswK = (u16*)alloc((size_t)HID * HID * 2);
    u16*  wswV = (u16*)alloc((size_t)HID * HID * 2);
    u16*  wswK2 = (u16*)alloc((size_t)HID * HID * 2);
    u16*  wswV2 = (u16*)alloc((size_t)HID * HID * 2);
    float* bkF2 = (float*)alloc(HID * 4);
    float* bvF2 = (float*)alloc(HID * 4);
    u16*  wswA = (u16*)alloc((size_t)9 * HID * HID * 2);
    if ((size_t)(p - (char*)d_ws) > ws_size) return; // clean fail -> zeros signature

    const float scale = 0.17677669529663687f;

    // ---- build 3 CSRs ----
    {
        const int* DL[3] = { ei_vt_d, ei_tv_d, ei_tt_d };
        const int* SL[3] = { ei_vt_s, ei_tv_s, ei_tt_s };
        int* RP[3] = { rp_vt, rp_tv, rp_tt };
        int* ES[3] = { es_vt, es_tv, es_tt };
        int ND[3] = { NT, NV, NT };
        for (int r = 0; r < 3; r++) {
            k_zero_i<<<256, 256, 0, stream>>>(cnt, ND[r]);
            k_hist<<<512, 256, 0, stream>>>(DL[r], cnt);
            k_scan<<<1, 1024, 0, stream>>>(cnt, RP[r], ND[r]);
            k_copy_i<<<256, 256, 0, stream>>>(RP[r], fill, ND[r]);
            k_scatter<<<512, 256, 0, stream>>>(DL[r], SL[r], fill, ES[r]);
        }
    }

    // ---- swizzle all static weights in one launch ----
    k_swz_multi<<<9 * 256, 256, 0, stream>>>(Wq, Wa, Ws1, wswA);

    k_in_proj<<<(NV + 15) / 16, 256, 0, stream>>>(x_v, W_in_v, b_in_v, hv, NV);
    k_in_proj<<<(NT + 15) / 16, 256, 0, stream>>>(x_t, W_in_t, b_in_t, ht, NT);

    const int GV = (NV + 15) / 16, GT = (NT + 15) / 16;

    for (int l = 0; l < NL; l++) {
        const float* Wk0 = Wk + (size_t)(l * 2 + 0) * HID * HID;
        const float* Wk1 = Wk + (size_t)(l * 2 + 1) * HID * HID;
        const float* bk0 = bk + (l * 2 + 0) * HID, *bk1 = bk + (l * 2 + 1) * HID;
        const float* Wv0 = Wv + (size_t)(l * 2 + 0) * HID * HID;
        const float* Wv1 = Wv + (size_t)(l * 2 + 1) * HID * HID;
        const float* bv0 = bv + (l * 2 + 0) * HID, *bv1 = bv + (l * 2 + 1) * HID;
        const float* bq0 = bq + (l * 2 + 0) * HID, *bq1 = bq + (l * 2 + 1) * HID;
        const u16* WqS0 = wswA + (size_t)(l * 2 + 0) * 65536;
        const u16* WqS1 = wswA + (size_t)(l * 2 + 1) * 65536;
        const u16* WaS0 = wswA + (size_t)(4 + l * 2 + 0) * 65536;
        const u16* WaS1 = wswA + (size_t)(4 + l * 2 + 1) * 65536;
        const float* A0 = a_rel + (size_t)(l * 3 + 0) * NH * DH * DH;
        const float* A1 = a_rel + (size_t)(l * 3 + 1) * NH * DH * DH;
        const float* A2 = a_rel + (size_t)(l * 3 + 2) * NH * DH * DH;
        const float* M0 = m_rel + (size_t)(l * 3 + 0) * NH * DH * DH;
        const float* M1 = m_rel + (size_t)(l * 3 + 1) * NH * DH * DH;
        const float* M2 = m_rel + (size_t)(l * 3 + 2) * NH * DH * DH;
        const float* P0 = p_rel + (size_t)(l * 3 + 0) * NH;
        const float* P1 = p_rel + (size_t)(l * 3 + 1) * NH;
        const float* P2 = p_rel + (size_t)(l * 3 + 2) * NH;

        // A. r0 (v->t) weights; fused q_v + k0 + v0 from OLD hv (one A read)
        k_fuse_w<<<NH, 256, 0, stream>>>(Wk0, bk0, A0, wswK, bkF);
        k_fuse_w<<<NH, 256, 0, stream>>>(Wv0, bv0, M0, wswV, bvF);
        k_mm3<<<GV, 256, 0, stream>>>(hv, WqS0, bq0, qv, wswK, bkF, kA0, wswV, bvF, vM0, NV);

        // B. r1 (t->v) weights; fused q_t + k1 + v1 from OLD ht (one A read)
        k_fuse_w<<<NH, 256, 0, stream>>>(Wk1, bk1, A1, wswK, bkF);
        k_fuse_w<<<NH, 256, 0, stream>>>(Wv1, bv1, M1, wswV, bvF);
        k_mm3<<<GT, 256, 0, stream>>>(ht, WqS1, bq1, qb, wswK, bkF, kA, wswV, bvF, vM, NT);

        // C. aggregate r1 into agg (dst = v)
        k_node_attn<<<(NV + 3) / 4, 256, 0, stream>>>(qv, kA, vM, rp_tv, es_tv, P1, scale, agg, NV);

        // D. update hv (old hv fully consumed)
        k_mm<2, 1><<<GV, 256, 0, stream>>>(agg, WaS0, ba + (l * 2 + 0) * HID, hv, skip + (l * 2 + 0), NV);

        // E. r2 (t->t) projections from OLD ht (kA/vM from r1 dead after C)
        k_fuse_w<<<NH, 256, 0, stream>>>(Wk1, bk1, A2, wswK2, bkF2);
        k_fuse_w<<<NH, 256, 0, stream>>>(Wv1, bv1, M2, wswV2, bvF2);
        k_mm2<<<GT, 256, 0, stream>>>(ht, wswK2, bkF2, kA, wswV2, bvF2, vM, NT);

        // F. combined dst=t aggregation: r0 (kA0/vM0) + r2 (kA/vM), one q read, one agg write
        k_node_attn2<<<(NT + 3) / 4, 256, 0, stream>>>(qb, kA0, vM0, rp_vt, es_vt, P0,
                                                       kA, vM, rp_tt, es_tt, P2, scale, agg, NT);

        // G. update ht
        k_mm<2, 1><<<GT, 256, 0, stream>>>(agg, WaS1, ba + (l * 2 + 1) * HID, ht, skip + (l * 2 + 1), NT);
    }

    k_vpart<<<1, 256, 0, stream>>>(hv, current, Ws1, bs1, vp);
    float* tpart = (float*)kA; // kA+vM contiguous = NT*HID*4 bytes
    k_mm<1, 0><<<GT, 256, 0, stream>>>(ht, wswA + (size_t)8 * 65536, nullptr, (void*)tpart, nullptr, NT);
    k_final<<<2048, 256, 0, stream>>>(tpart, vp, Ws2, bs2, (float*)d_out);
}

// Round 18
// 1096.856 us; speedup vs baseline: 1.6911x; 1.0727x over previous
//
#include <hip/hip_runtime.h>
#include <hip/hip_bf16.h>
#include <math.h>

#define HID 256
#define NH 8
#define DH 32
#define NL 2
#define NV 20000
#define NT 50000
#define NE 100000
#define NC 8
#define FIN 64

typedef unsigned short u16;
typedef unsigned int u32;
typedef short s16x8 __attribute__((ext_vector_type(8)));
typedef float f32x4 __attribute__((ext_vector_type(4)));

__device__ __forceinline__ float bf2f(u16 u) { return __uint_as_float(((u32)u) << 16); }
__device__ __forceinline__ u16 f2bf(float f) {
    u32 x = __float_as_uint(f);
    u32 r = ((x >> 16) & 1u) + 0x7fffu;
    return (u16)((x + r) >> 16);
}
__device__ __forceinline__ void up2(u32 u, float& a, float& b) {
    a = __uint_as_float(u << 16);
    b = __uint_as_float(u & 0xffff0000u);
}
__device__ __forceinline__ s16x8 gelu8(s16x8 a) {
    s16x8 r;
#pragma unroll
    for (int i = 0; i < 8; i++) {
        float v = bf2f((u16)a[i]);
        v = 0.5f * v * (1.f + erff(v * 0.70710678118654752f));
        r[i] = (short)f2bf(v);
    }
    return r;
}

// ---------------- zero fill ----------------
__global__ void k_zero_i(int* __restrict__ p, int n) {
    for (int i = blockIdx.x * 256 + threadIdx.x; i < n; i += gridDim.x * 256) p[i] = 0;
}

// ---------------- batched histogram of 3 dst arrays ----------------
__global__ void k_hist3(const int* __restrict__ d0, const int* __restrict__ d1, const int* __restrict__ d2,
                        int* __restrict__ cnt3) {
    int r = blockIdx.x >> 9;        // 0..2
    int b = blockIdx.x & 511;
    const int* dst = (r == 0) ? d0 : (r == 1) ? d1 : d2;
    int* cnt = cnt3 + (size_t)r * NT;
    for (int e = b * 256 + threadIdx.x; e < NE; e += 512 * 256)
        atomicAdd(&cnt[dst[e]], 1);
}

// ---------------- batched serial scans: 3 blocks, one per relation (run concurrently) ------
__global__ __launch_bounds__(1024) void k_scan3(const int* __restrict__ cnt3,
                                                int* __restrict__ rp0, int* __restrict__ rp1, int* __restrict__ rp2) {
    int r = blockIdx.x;
    const int* cnt = cnt3 + (size_t)r * NT;
    int* rp = (r == 0) ? rp0 : (r == 1) ? rp1 : rp2;
    int n = (r == 1) ? NV : NT;
    __shared__ int wsum[16];
    __shared__ int carry_s;
    int t = threadIdx.x, lane = t & 63, wv = t >> 6;
    if (t == 0) { carry_s = 0; rp[0] = 0; }
    __syncthreads();
    for (int base = 0; base < n; base += 1024) {
        int v = (base + t < n) ? cnt[base + t] : 0;
        int x = v;
#pragma unroll
        for (int off = 1; off < 64; off <<= 1) {
            int y = __shfl_up(x, off, 64);
            if (lane >= off) x += y;
        }
        if (lane == 63) wsum[wv] = x;
        __syncthreads();
        if (wv == 0 && lane < 16) {
            int s = wsum[lane];
#pragma unroll
            for (int off = 1; off < 16; off <<= 1) {
                int y = __shfl_up(s, off, 64);
                if (lane >= off) s += y;
            }
            wsum[lane] = s;
        }
        __syncthreads();
        int prefix = carry_s + (wv > 0 ? wsum[wv - 1] : 0);
        if (base + t < n) rp[base + t + 1] = prefix + x;
        __syncthreads();
        if (t == 0) carry_s += wsum[15];
        __syncthreads();
    }
}

// ---------------- batched fill copy: fill3[r][i] = rp_r[i] ----------------
__global__ void k_copy3(const int* __restrict__ rp0, const int* __restrict__ rp1, const int* __restrict__ rp2,
                        int* __restrict__ fill3) {
    int r = blockIdx.x >> 8;
    int b = blockIdx.x & 255;
    const int* rp = (r == 0) ? rp0 : (r == 1) ? rp1 : rp2;
    int n = (r == 1) ? NV : NT;
    int* fill = fill3 + (size_t)r * NT;
    for (int i = b * 256 + threadIdx.x; i < n; i += 256 * 256) fill[i] = rp[i];
}

// ---------------- batched scatter ----------------
__global__ void k_scatter3(const int* __restrict__ d0, const int* __restrict__ s0,
                           const int* __restrict__ d1, const int* __restrict__ s1,
                           const int* __restrict__ d2, const int* __restrict__ s2,
                           int* __restrict__ fill3,
                           int* __restrict__ es0, int* __restrict__ es1, int* __restrict__ es2) {
    int r = blockIdx.x >> 9;
    int b = blockIdx.x & 511;
    const int* dst = (r == 0) ? d0 : (r == 1) ? d1 : d2;
    const int* src = (r == 0) ? s0 : (r == 1) ? s1 : s2;
    int* fill = fill3 + (size_t)r * NT;
    int* es = (r == 0) ? es0 : (r == 1) ? es1 : es2;
    for (int e = b * 256 + threadIdx.x; e < NE; e += 512 * 256) {
        int d = dst[e];
        int p = atomicAdd(&fill[d], 1);
        es[p] = src[e];
    }
}

// ---------------- input projection ----------------
__global__ __launch_bounds__(256) void k_in_proj(const float* __restrict__ X, const float* __restrict__ W,
                          const float* __restrict__ b, u16* __restrict__ Y, int N) {
    const int NPB = 16;
    __shared__ float xs[NPB][FIN];
    int n0 = blockIdx.x * NPB;
    int t = threadIdx.x;
    for (int idx = t; idx < NPB * FIN; idx += 256) {
        int i = idx >> 6, c = idx & 63;
        int n = n0 + i;
        xs[i][c] = (n < N) ? X[(size_t)n * FIN + c] : 0.f;
    }
    __syncthreads();
    float acc[NPB];
#pragma unroll
    for (int i = 0; i < NPB; i++) acc[i] = 0.f;
    for (int c = 0; c < FIN; c++) {
        float w = W[c * HID + t];
#pragma unroll
        for (int i = 0; i < NPB; i++) acc[i] += xs[i][c] * w;
    }
    float bb = b[t];
    for (int i = 0; i < NPB; i++) {
        int n = n0 + i;
        if (n < N) Y[(size_t)n * HID + t] = f2bf(fmaxf(acc[i] + bb, 0.f));
    }
}

// swizzle index for MFMA B fragment: given (k,n) -> flat idx in Wsw
__device__ __forceinline__ int swz_idx(int k, int n) {
    int ks = k >> 5, r = k & 31;
    int j = r & 7;
    int l = ((r >> 3) << 4) | (n & 15);
    int nt = n >> 4;
    return ((ks * 16 + nt) * 64 + l) * 8 + j;
}

// ---------------- fuse rel matrix into projection weight, emit SWIZZLED bf16 ----------------
__global__ __launch_bounds__(256) void k_fuse_w(const float* __restrict__ W, const float* __restrict__ b,
                        const float* __restrict__ R, u16* __restrict__ Wsw, float* __restrict__ bout) {
    int h = blockIdx.x; // 8 blocks
    __shared__ float sR[DH * DH];
    int t = threadIdx.x;
    for (int idx = t; idx < DH * DH; idx += 256) sR[idx] = R[h * DH * DH + idx];
    __syncthreads();
    int f = t & 31, c0 = t >> 5;
    for (int c = c0; c < HID; c += 8) {
        float acc = 0.f;
#pragma unroll
        for (int d = 0; d < DH; d++) acc += W[c * HID + h * DH + d] * sR[d * DH + f];
        Wsw[swz_idx(c, h * DH + f)] = f2bf(acc);
    }
    if (t < DH) {
        float acc = 0.f;
#pragma unroll
        for (int d = 0; d < DH; d++) acc += b[h * DH + d] * sR[d * DH + t];
        bout[h * DH + t] = acc;
    }
}

// ---------------- batched swizzle of 9 static weights: Wq[0..3], Wa[0..3], Ws1 ----------------
__global__ __launch_bounds__(256) void k_swz_multi(const float* __restrict__ Wq, const float* __restrict__ Wa,
                                                   const float* __restrict__ Ws1, u16* __restrict__ out) {
    int slot = blockIdx.x >> 8;
    int idx = ((blockIdx.x & 255) << 8) | threadIdx.x; // 0..65535
    const float* src = (slot < 4) ? (Wq + (size_t)slot * 65536)
                     : (slot < 8) ? (Wa + (size_t)(slot - 4) * 65536)
                                  : Ws1;
    int j = idx & 7, l = (idx >> 3) & 63, nt = (idx >> 9) & 15, ks = idx >> 13;
    int k = ks * 32 + (l >> 4) * 8 + j;
    int n = nt * 16 + (l & 15);
    out[(size_t)slot * 65536 + idx] = f2bf(src[k * HID + n]);
}

// ---------------- MFMA GEMM, slim-wave ----------------
// MODE 0: bf16+bias. MODE 1: f32, no bias. MODE 2: skip-mix bf16. MODE 3: bf16, no bias.
template <int MODE, int GELU>
__global__ __launch_bounds__(256) void k_mm(const u16* __restrict__ X, const u16* __restrict__ Wsw,
                                            const float* __restrict__ bias, void* __restrict__ Y,
                                            const float* __restrict__ skip_, int N) {
    int tid = threadIdx.x;
    int w = tid >> 6, lane = tid & 63;
    int r0 = blockIdx.x * 16;
    int rA = r0 + (lane & 15);
    int koffg = lane >> 4;
    s16x8 a[8];
    if (rA < N) {
        const s16x8* ap = (const s16x8*)(X + (size_t)rA * HID) + koffg;
#pragma unroll
        for (int ks = 0; ks < 8; ks++) a[ks] = ap[ks * 4];
    } else {
#pragma unroll
        for (int ks = 0; ks < 8; ks++) a[ks] = (s16x8){0, 0, 0, 0, 0, 0, 0, 0};
    }
    if (GELU) {
#pragma unroll
        for (int ks = 0; ks < 8; ks++) a[ks] = gelu8(a[ks]);
    }
    f32x4 acc[4];
#pragma unroll
    for (int nt = 0; nt < 4; nt++) acc[nt] = (f32x4){0.f, 0.f, 0.f, 0.f};
    const s16x8* wp = (const s16x8*)Wsw;
#pragma unroll
    for (int ks = 0; ks < 8; ks++) {
        const s16x8* wq = wp + (size_t)ks * 16 * 64 + lane;
#pragma unroll
        for (int nt = 0; nt < 4; nt++) {
            s16x8 b = wq[(w * 4 + nt) * 64];
            acc[nt] = __builtin_amdgcn_mfma_f32_16x16x32_bf16(a[ks], b, acc[nt], 0, 0, 0);
        }
    }
    int colb = lane & 15;
    int rowb = r0 + koffg * 4;
    float beta = 0.f, ombeta = 0.f;
    if (MODE == 2) { beta = 1.f / (1.f + expf(-skip_[0])); ombeta = 1.f - beta; }
#pragma unroll
    for (int nt = 0; nt < 4; nt++) {
        int col = w * 64 + nt * 16 + colb;
        float bb = (MODE == 1 || MODE == 3) ? 0.f : bias[col];
#pragma unroll
        for (int j = 0; j < 4; j++) {
            int row = rowb + j;
            if (row < N) {
                float v = acc[nt][j] + bb;
                if (MODE == 0 || MODE == 3) {
                    ((u16*)Y)[(size_t)row * HID + col] = f2bf(v);
                } else if (MODE == 1) {
                    ((float*)Y)[(size_t)row * HID + col] = v;
                } else {
                    u16* hp = (u16*)Y + (size_t)row * HID + col;
                    *hp = f2bf(beta * v + ombeta * bf2f(*hp));
                }
            }
        }
    }
}

// ---------------- dual-B slim-wave MFMA GEMM (A loaded once) ----------------
__global__ __launch_bounds__(256) void k_mm2(const u16* __restrict__ X,
                                             const u16* __restrict__ W1, const float* __restrict__ b1, u16* __restrict__ Y1,
                                             const u16* __restrict__ W2, const float* __restrict__ b2, u16* __restrict__ Y2,
                                             int N) {
    int tid = threadIdx.x;
    int w = tid >> 6, lane = tid & 63;
    int r0 = blockIdx.x * 16;
    int rA = r0 + (lane & 15);
    int koffg = lane >> 4;
    s16x8 a[8];
    if (rA < N) {
        const s16x8* ap = (const s16x8*)(X + (size_t)rA * HID) + koffg;
#pragma unroll
        for (int ks = 0; ks < 8; ks++) a[ks] = ap[ks * 4];
    } else {
#pragma unroll
        for (int ks = 0; ks < 8; ks++) a[ks] = (s16x8){0, 0, 0, 0, 0, 0, 0, 0};
    }
    int colb = lane & 15;
    int rowb = r0 + koffg * 4;
#pragma unroll
    for (int pass = 0; pass < 2; pass++) {
        const u16* Wsw = pass ? W2 : W1;
        const float* bias = pass ? b2 : b1;
        u16* Y = pass ? Y2 : Y1;
        f32x4 acc[4];
#pragma unroll
        for (int nt = 0; nt < 4; nt++) acc[nt] = (f32x4){0.f, 0.f, 0.f, 0.f};
        const s16x8* wp = (const s16x8*)Wsw;
#pragma unroll
        for (int ks = 0; ks < 8; ks++) {
            const s16x8* wq = wp + (size_t)ks * 16 * 64 + lane;
#pragma unroll
            for (int nt = 0; nt < 4; nt++) {
                s16x8 b = wq[(w * 4 + nt) * 64];
                acc[nt] = __builtin_amdgcn_mfma_f32_16x16x32_bf16(a[ks], b, acc[nt], 0, 0, 0);
            }
        }
#pragma unroll
        for (int nt = 0; nt < 4; nt++) {
            int col = w * 64 + nt * 16 + colb;
            float bb = bias[col];
#pragma unroll
            for (int j = 0; j < 4; j++) {
                int row = rowb + j;
                if (row < N) Y[(size_t)row * HID + col] = f2bf(acc[nt][j] + bb);
            }
        }
    }
}

// ---------------- triple-B slim-wave MFMA GEMM: q + k + v from one A read ----------------
__global__ __launch_bounds__(256) void k_mm3(const u16* __restrict__ X,
                                             const u16* __restrict__ W0, const float* __restrict__ b0, u16* __restrict__ Y0,
                                             const u16* __restrict__ W1, const float* __restrict__ b1, u16* __restrict__ Y1,
                                             const u16* __restrict__ W2, const float* __restrict__ b2, u16* __restrict__ Y2,
                                             int N) {
    int tid = threadIdx.x;
    int w = tid >> 6, lane = tid & 63;
    int r0 = blockIdx.x * 16;
    int rA = r0 + (lane & 15);
    int koffg = lane >> 4;
    s16x8 a[8];
    if (rA < N) {
        const s16x8* ap = (const s16x8*)(X + (size_t)rA * HID) + koffg;
#pragma unroll
        for (int ks = 0; ks < 8; ks++) a[ks] = ap[ks * 4];
    } else {
#pragma unroll
        for (int ks = 0; ks < 8; ks++) a[ks] = (s16x8){0, 0, 0, 0, 0, 0, 0, 0};
    }
    int colb = lane & 15;
    int rowb = r0 + koffg * 4;
#pragma unroll
    for (int pass = 0; pass < 3; pass++) {
        const u16* Wsw = (pass == 0) ? W0 : (pass == 1) ? W1 : W2;
        const float* bias = (pass == 0) ? b0 : (pass == 1) ? b1 : b2;
        u16* Y = (pass == 0) ? Y0 : (pass == 1) ? Y1 : Y2;
        f32x4 acc[4];
#pragma unroll
        for (int nt = 0; nt < 4; nt++) acc[nt] = (f32x4){0.f, 0.f, 0.f, 0.f};
        const s16x8* wp = (const s16x8*)Wsw;
#pragma unroll
        for (int ks = 0; ks < 8; ks++) {
            const s16x8* wq = wp + (size_t)ks * 16 * 64 + lane;
#pragma unroll
            for (int nt = 0; nt < 4; nt++) {
                s16x8 b = wq[(w * 4 + nt) * 64];
                acc[nt] = __builtin_amdgcn_mfma_f32_16x16x32_bf16(a[ks], b, acc[nt], 0, 0, 0);
            }
        }
#pragma unroll
        for (int nt = 0; nt < 4; nt++) {
            int col = w * 64 + nt * 16 + colb;
            float bb = bias[col];
#pragma unroll
            for (int j = 0; j < 4; j++) {
                int row = rowb + j;
                if (row < N) Y[(size_t)row * HID + col] = f2bf(acc[nt][j] + bb);
            }
        }
    }
}

// ---------------- online-softmax over one CSR with 1-edge-deep prefetch ----------------
__device__ __forceinline__ void attn_pass(const u16* __restrict__ kA, const u16* __restrict__ vM,
                                          const int* __restrict__ es, int jb, int je,
                                          float q0, float q1, float q2, float q3, float ph, int lane4,
                                          float& o0, float& o1, float& o2, float& o3) {
    float m = -INFINITY, ss = 0.f, a0 = 0.f, a1 = 0.f, a2 = 0.f, a3 = 0.f;
    uint2 kuN = {0, 0}, vuN = {0, 0};
    if (jb < je) {
        int s0 = es[jb];
        kuN = *(const uint2*)(kA + (size_t)s0 * HID + lane4);
        vuN = *(const uint2*)(vM + (size_t)s0 * HID + lane4);
    }
    for (int j = jb; j < je; j++) {
        uint2 ku = kuN, vu = vuN;
        if (j + 1 < je) {
            int s1 = es[j + 1];
            kuN = *(const uint2*)(kA + (size_t)s1 * HID + lane4);
            vuN = *(const uint2*)(vM + (size_t)s1 * HID + lane4);
        }
        float k0, k1, k2, k3; up2(ku.x, k0, k1); up2(ku.y, k2, k3);
        float part = q0 * k0 + q1 * k1 + q2 * k2 + q3 * k3;
        part += __shfl_xor(part, 1, 64);
        part += __shfl_xor(part, 2, 64);
        part += __shfl_xor(part, 4, 64);
        float logit = part * ph;
        float nm = fmaxf(m, logit);
        float corr = expf(m - nm);
        float ee = expf(logit - nm);
        float v0, v1, v2, v3; up2(vu.x, v0, v1); up2(vu.y, v2, v3);
        ss = ss * corr + ee;
        a0 = a0 * corr + ee * v0; a1 = a1 * corr + ee * v1;
        a2 = a2 * corr + ee * v2; a3 = a3 * corr + ee * v3;
        m = nm;
    }
    float inv = 1.f / (ss + 1e-16f);
    o0 += a0 * inv; o1 += a1 * inv; o2 += a2 * inv; o3 += a3 * inv;
}

// ---------------- single-relation node attention ----------------
__global__ __launch_bounds__(256) void k_node_attn(
        const u16* __restrict__ q, const u16* __restrict__ kA, const u16* __restrict__ vM,
        const int* __restrict__ rp, const int* __restrict__ es,
        const float* __restrict__ P, float scale,
        u16* __restrict__ agg, int Nd) {
    int node = blockIdx.x * 4 + (threadIdx.x >> 6);
    if (node >= Nd) return;
    int lane = threadIdx.x & 63;
    float ph = P[lane >> 3] * scale;
    uint2 qu = *(const uint2*)(q + (size_t)node * HID + lane * 4);
    float q0, q1, q2, q3; up2(qu.x, q0, q1); up2(qu.y, q2, q3);
    float o0 = 0.f, o1 = 0.f, o2 = 0.f, o3 = 0.f;
    attn_pass(kA, vM, es, rp[node], rp[node + 1], q0, q1, q2, q3, ph, lane * 4, o0, o1, o2, o3);
    u16* ap = agg + (size_t)node * HID + lane * 4;
    ap[0] = f2bf(o0); ap[1] = f2bf(o1); ap[2] = f2bf(o2); ap[3] = f2bf(o3);
}

// ---------------- dual-relation node attention (dst=t: r0 + r2 summed in f32) ----------------
__global__ __launch_bounds__(256) void k_node_attn2(
        const u16* __restrict__ q,
        const u16* __restrict__ kA0, const u16* __restrict__ vM0,
        const int* __restrict__ rp0, const int* __restrict__ es0, const float* __restrict__ P0,
        const u16* __restrict__ kA1, const u16* __restrict__ vM1,
        const int* __restrict__ rp1, const int* __restrict__ es1, const float* __restrict__ P1,
        float scale, u16* __restrict__ agg, int Nd) {
    int node = blockIdx.x * 4 + (threadIdx.x >> 6);
    if (node >= Nd) return;
    int lane = threadIdx.x & 63;
    int h = lane >> 3;
    float ph0 = P0[h] * scale, ph1 = P1[h] * scale;
    uint2 qu = *(const uint2*)(q + (size_t)node * HID + lane * 4);
    float q0, q1, q2, q3; up2(qu.x, q0, q1); up2(qu.y, q2, q3);
    float o0 = 0.f, o1 = 0.f, o2 = 0.f, o3 = 0.f;
    attn_pass(kA0, vM0, es0, rp0[node], rp0[node + 1], q0, q1, q2, q3, ph0, lane * 4, o0, o1, o2, o3);
    attn_pass(kA1, vM1, es1, rp1[node], rp1[node + 1], q0, q1, q2, q3, ph1, lane * 4, o0, o1, o2, o3);
    u16* ap = agg + (size_t)node * HID + lane * 4;
    ap[0] = f2bf(o0); ap[1] = f2bf(o1); ap[2] = f2bf(o2); ap[3] = f2bf(o3);
}

// ---------------- vpart ----------------
__global__ void k_vpart(const u16* __restrict__ hv, const int* __restrict__ current,
                        const float* __restrict__ Ws1, const float* __restrict__ bs1,
                        float* __restrict__ vpart) {
    __shared__ float row[HID];
    int t = threadIdx.x;
    for (int c = 0; c < NC; c++) {
        int n = current[c * 2];
        row[t] = bf2f(hv[(size_t)n * HID + t]);
        __syncthreads();
        float acc = 0.f;
        for (int i = 0; i < HID; i++) acc += row[i] * Ws1[(size_t)(HID + i) * HID + t];
        vpart[c * HID + t] = acc + bs1[t];
        __syncthreads();
    }
}

// ---------------- final: tpart now bf16 ----------------
__global__ __launch_bounds__(256) void k_final(const u16* __restrict__ tpart, const float* __restrict__ vpart,
                        const float* __restrict__ Ws2, const float* __restrict__ bs2,
                        float* __restrict__ out) {
    __shared__ float vp[NC * HID];
    int t = threadIdx.x;
    for (int idx = t; idx < NC * HID; idx += 256) vp[idx] = vpart[idx];
    __syncthreads();
    int lane = t & 63, w = t >> 6;
    float w20[4], w21[4];
#pragma unroll
    for (int i = 0; i < 4; i++) {
        w20[i] = Ws2[(lane + 64 * i) * 2 + 0];
        w21[i] = Ws2[(lane + 64 * i) * 2 + 1];
    }
    float b0 = bs2[0], b1 = bs2[1];
    for (int n = blockIdx.x * 4 + w; n < NT; n += gridDim.x * 4) {
        float tp[4];
#pragma unroll
        for (int i = 0; i < 4; i++) tp[i] = bf2f(tpart[(size_t)n * HID + lane + 64 * i]);
#pragma unroll
        for (int c = 0; c < NC; c++) {
            float a0 = 0.f, a1 = 0.f;
#pragma unroll
            for (int i = 0; i < 4; i++) {
                float hm = fmaxf(tp[i] + vp[c * HID + lane + 64 * i], 0.f);
                a0 += hm * w20[i];
                a1 += hm * w21[i];
            }
#pragma unroll
            for (int off = 32; off >= 1; off >>= 1) {
                a0 += __shfl_xor(a0, off, 64);
                a1 += __shfl_xor(a1, off, 64);
            }
            if (lane == 0) {
                out[(size_t)c * NT + n] = a0 + b0;
                float z = a1 + b1;
                out[(size_t)NC * NT + (size_t)c * NT + n] = 1.f / (1.f + expf(-z));
            }
        }
    }
}

extern "C" void kernel_launch(void* const* d_in, const int* in_sizes, int n_in,
                              void* d_out, int out_size, void* d_ws, size_t ws_size,
                              hipStream_t stream) {
    (void)in_sizes; (void)n_in; (void)out_size;
    const float* x_v    = (const float*)d_in[0];
    const float* x_t    = (const float*)d_in[1];
    const int* ei_vt_s  = (const int*)d_in[2];
    const int* ei_vt_d  = (const int*)d_in[3];
    const int* ei_tv_s  = (const int*)d_in[4];
    const int* ei_tv_d  = (const int*)d_in[5];
    const int* ei_tt_s  = (const int*)d_in[6];
    const int* ei_tt_d  = (const int*)d_in[7];
    const int* current  = (const int*)d_in[8];
    const float* W_in_v = (const float*)d_in[9];
    const float* b_in_v = (const float*)d_in[10];
    const float* W_in_t = (const float*)d_in[11];
    const float* b_in_t = (const float*)d_in[12];
    const float* Wk     = (const float*)d_in[13];
    const float* bk     = (const float*)d_in[14];
    const float* Wq     = (const float*)d_in[15];
    const float* bq     = (const float*)d_in[16];
    const float* Wv     = (const float*)d_in[17];
    const float* bv     = (const float*)d_in[18];
    const float* Wa     = (const float*)d_in[19];
    const float* ba     = (const float*)d_in[20];
    const float* skip   = (const float*)d_in[21];
    const float* a_rel  = (const float*)d_in[22];
    const float* m_rel  = (const float*)d_in[23];
    const float* p_rel  = (const float*)d_in[24];
    const float* Ws1    = (const float*)d_in[25];
    const float* bs1    = (const float*)d_in[26];
    const float* Ws2    = (const float*)d_in[27];
    const float* bs2    = (const float*)d_in[28];

    char* p = (char*)d_ws;
    auto alloc = [&](size_t bytes) -> char* {
        char* r = p;
        p += (bytes + 255) & ~(size_t)255;
        return r;
    };
    u16* hv   = (u16*)alloc((size_t)NV * HID * 2);
    u16* ht   = (u16*)alloc((size_t)NT * HID * 2);
    u16* qb   = (u16*)alloc((size_t)NT * HID * 2);
    u16* qv   = (u16*)alloc((size_t)NV * HID * 2);
    u16* kA   = (u16*)alloc((size_t)NT * HID * 2); // reused as bf16 tpart at the end
    u16* vM   = (u16*)alloc((size_t)NT * HID * 2);
    u16* kA0  = (u16*)alloc((size_t)NV * HID * 2);
    u16* vM0  = (u16*)alloc((size_t)NV * HID * 2);
    u16* agg  = (u16*)alloc((size_t)NT * HID * 2);
    int* rp_vt = (int*)alloc((size_t)(NT + 1) * 4);
    int* rp_tv = (int*)alloc((size_t)(NV + 1) * 4);
    int* rp_tt = (int*)alloc((size_t)(NT + 1) * 4);
    int* es_vt = (int*)alloc((size_t)NE * 4);
    int* es_tv = (int*)alloc((size_t)NE * 4);
    int* es_tt = (int*)alloc((size_t)NE * 4);
    int* cnt3  = (int*)alloc((size_t)3 * NT * 4);
    int* fill3 = (int*)alloc((size_t)3 * NT * 4);
    float* vp  = (float*)alloc((size_t)NC * HID * 4);
    float* bkF = (float*)alloc(HID * 4);
    float* bvF = (float*)alloc(HID * 4);
    u16*  wswK = (u16*)alloc((size_t)HID * HID * 2);
    u16*  wswV = (u16*)alloc((size_t)HID * HID * 2);
    u16*  wswK2 = (u16*)alloc((size_t)HID * HID * 2);
    u16*  wswV2 = (u16*)alloc((size_t)HID * HID * 2);
    float* bkF2 = (float*)alloc(HID * 4);
    float* bvF2 = (float*)alloc(HID * 4);
    u16*  wswA = (u16*)alloc((size_t)9 * HID * HID * 2);
    if ((size_t)(p - (char*)d_ws) > ws_size) return; // clean fail -> zeros signature

    const float scale = 0.17677669529663687f;

    // ---- build 3 CSRs (batched: 5 launches, scans concurrent) ----
    k_zero_i<<<256, 256, 0, stream>>>(cnt3, 3 * NT);
    k_hist3<<<3 * 512, 256, 0, stream>>>(ei_vt_d, ei_tv_d, ei_tt_d, cnt3);
    k_scan3<<<3, 1024, 0, stream>>>(cnt3, rp_vt, rp_tv, rp_tt);
    k_copy3<<<3 * 256, 256, 0, stream>>>(rp_vt, rp_tv, rp_tt, fill3);
    k_scatter3<<<3 * 512, 256, 0, stream>>>(ei_vt_d, ei_vt_s, ei_tv_d, ei_tv_s, ei_tt_d, ei_tt_s,
                                            fill3, es_vt, es_tv, es_tt);

    // ---- swizzle all static weights in one launch ----
    k_swz_multi<<<9 * 256, 256, 0, stream>>>(Wq, Wa, Ws1, wswA);

    k_in_proj<<<(NV + 15) / 16, 256, 0, stream>>>(x_v, W_in_v, b_in_v, hv, NV);
    k_in_proj<<<(NT + 15) / 16, 256, 0, stream>>>(x_t, W_in_t, b_in_t, ht, NT);

    const int GV = (NV + 15) / 16, GT = (NT + 15) / 16;

    for (int l = 0; l < NL; l++) {
        const float* Wk0 = Wk + (size_t)(l * 2 + 0) * HID * HID;
        const float* Wk1 = Wk + (size_t)(l * 2 + 1) * HID * HID;
        const float* bk0 = bk + (l * 2 + 0) * HID, *bk1 = bk + (l * 2 + 1) * HID;
        const float* Wv0 = Wv + (size_t)(l * 2 + 0) * HID * HID;
        const float* Wv1 = Wv + (size_t)(l * 2 + 1) * HID * HID;
        const float* bv0 = bv + (l * 2 + 0) * HID, *bv1 = bv + (l * 2 + 1) * HID;
        const float* bq0 = bq + (l * 2 + 0) * HID, *bq1 = bq + (l * 2 + 1) * HID;
        const u16* WqS0 = wswA + (size_t)(l * 2 + 0) * 65536;
        const u16* WqS1 = wswA + (size_t)(l * 2 + 1) * 65536;
        const u16* WaS0 = wswA + (size_t)(4 + l * 2 + 0) * 65536;
        const u16* WaS1 = wswA + (size_t)(4 + l * 2 + 1) * 65536;
        const float* A0 = a_rel + (size_t)(l * 3 + 0) * NH * DH * DH;
        const float* A1 = a_rel + (size_t)(l * 3 + 1) * NH * DH * DH;
        const float* A2 = a_rel + (size_t)(l * 3 + 2) * NH * DH * DH;
        const float* M0 = m_rel + (size_t)(l * 3 + 0) * NH * DH * DH;
        const float* M1 = m_rel + (size_t)(l * 3 + 1) * NH * DH * DH;
        const float* M2 = m_rel + (size_t)(l * 3 + 2) * NH * DH * DH;
        const float* P0 = p_rel + (size_t)(l * 3 + 0) * NH;
        const float* P1 = p_rel + (size_t)(l * 3 + 1) * NH;
        const float* P2 = p_rel + (size_t)(l * 3 + 2) * NH;

        // A. r0 (v->t) weights; fused q_v + k0 + v0 from OLD hv (one A read)
        k_fuse_w<<<NH, 256, 0, stream>>>(Wk0, bk0, A0, wswK, bkF);
        k_fuse_w<<<NH, 256, 0, stream>>>(Wv0, bv0, M0, wswV, bvF);
        k_mm3<<<GV, 256, 0, stream>>>(hv, WqS0, bq0, qv, wswK, bkF, kA0, wswV, bvF, vM0, NV);

        // B. r1 (t->v) weights; fused q_t + k1 + v1 from OLD ht (one A read)
        k_fuse_w<<<NH, 256, 0, stream>>>(Wk1, bk1, A1, wswK, bkF);
        k_fuse_w<<<NH, 256, 0, stream>>>(Wv1, bv1, M1, wswV, bvF);
        k_mm3<<<GT, 256, 0, stream>>>(ht, WqS1, bq1, qb, wswK, bkF, kA, wswV, bvF, vM, NT);

        // C. aggregate r1 into agg (dst = v)
        k_node_attn<<<(NV + 3) / 4, 256, 0, stream>>>(qv, kA, vM, rp_tv, es_tv, P1, scale, agg, NV);

        // D. update hv (old hv fully consumed)
        k_mm<2, 1><<<GV, 256, 0, stream>>>(agg, WaS0, ba + (l * 2 + 0) * HID, hv, skip + (l * 2 + 0), NV);

        // E. r2 (t->t) projections from OLD ht (kA/vM from r1 dead after C)
        k_fuse_w<<<NH, 256, 0, stream>>>(Wk1, bk1, A2, wswK2, bkF2);
        k_fuse_w<<<NH, 256, 0, stream>>>(Wv1, bv1, M2, wswV2, bvF2);
        k_mm2<<<GT, 256, 0, stream>>>(ht, wswK2, bkF2, kA, wswV2, bvF2, vM, NT);

        // F. combined dst=t aggregation: r0 (kA0/vM0) + r2 (kA/vM), one q read, one agg write
        k_node_attn2<<<(NT + 3) / 4, 256, 0, stream>>>(qb, kA0, vM0, rp_vt, es_vt, P0,
                                                       kA, vM, rp_tt, es_tt, P2, scale, agg, NT);

        // G. update ht
        k_mm<2, 1><<<GT, 256, 0, stream>>>(agg, WaS1, ba + (l * 2 + 1) * HID, ht, skip + (l * 2 + 1), NT);
    }

    k_vpart<<<1, 256, 0, stream>>>(hv, current, Ws1, bs1, vp);
    u16* tpart = kA; // bf16 tpart
    k_mm<3, 0><<<GT, 256, 0, stream>>>(ht, wswA + (size_t)8 * 65536, nullptr, (void*)tpart, nullptr, NT);
    k_final<<<2048, 256, 0, stream>>>(tpart, vp, Ws2, bs2, (float*)d_out);
}